// Round 6
// baseline (448.465 us; speedup 1.0000x reference)
//
#include <hip/hip_runtime.h>
#include <hip/hip_cooperative_groups.h>
#include <math.h>

namespace cg = cooperative_groups;

// GaussianMixture log-likelihood: ll[n] = logsumexp_m( wlog[m] - dx^T G_m dx )
// R11: ONE cooperative kernel (dispatch overhead ~10us each; R10 proved +4
// dispatches = +31us). Phases: zero-hist | hist + block0 C-prep | scan |
// scatter | compute, separated by grid.sync(). Pruning fixed vs R10:
//  - MORTON order for sample cells (64x64) and comp cells (16x16): tight
//    wave bboxes (R10's row-major straddle gave 4.0-wide bboxes -> no skip)
//  - best-first chunk selection + precomputed lower-bound anchor anc0
//    (= max_c lb_c; the lb-achieving chunk can never be skipped -> bound is
//    non-circular and safe before any processing)
//  - T_SKIP=16 (skipped mass <= 2048*2^-16 ~ 3% rel ~ Schraudolph's own err)
//  - dynamic tile counter (1024 tiles of 128 samples) for load balance
// Fallback: ws too small / M!=2048 / no coop -> exact 2-kernel R9b path.
// Max trees stay COMPLETE (R5 NaN lesson); coefficient loads wave-uniform
// (R3 lesson); selection arrays statically indexed (scratch rule).

#if __has_builtin(__builtin_amdgcn_exp2f)
#define EXP2(x) __builtin_amdgcn_exp2f(x)
#else
#define EXP2(x) exp2f(x)
#endif

typedef float v2f __attribute__((ext_vector_type(2)));
typedef int   i2v __attribute__((ext_vector_type(2)));
typedef float v4f __attribute__((ext_vector_type(4)));
typedef int   i4v __attribute__((ext_vector_type(4)));

#if __has_builtin(__builtin_elementwise_max)
#define VMAX(a, b) __builtin_elementwise_max(a, b)
#else
static __device__ inline v2f VMAX(v2f a, v2f b) {
  v2f r; r.x = fmaxf(a.x, b.x); r.y = fmaxf(a.y, b.y); return r;
}
static __device__ inline v4f VMAX(v4f a, v4f b) {
  v4f r; r.x = fmaxf(a.x, b.x); r.y = fmaxf(a.y, b.y);
  r.z = fmaxf(a.z, b.z); r.w = fmaxf(a.w, b.w); return r;
}
#endif

// Schraudolph exp2 (fp32): y = bitcast(int(x*2^23 + 127*2^23 - C)), C=366393
#define SCH_K1   8388608.0f      // 2^23
#define SCH_K2   1064986823.0f   // 127*2^23 - 366393
#define SCH_TMIN 58353856.0f     // SCH_K2 - 120*2^23 (clamp keeps cvt valid)

#define SPLIT 8
#define CH   16    // comps per chunk
#define CPW  16    // chunks per wave (requires M == 2048)
#define SC   64    // sample cell grid (SCxSC over [-2,2]^2)
#define SCELLS (SC * SC)
#define T_SKIP 16.0f

// ---------- morton ----------
static __device__ __forceinline__ unsigned p1b1(unsigned v) {
  v &= 0xFFu;
  v = (v | (v << 4)) & 0x0F0Fu;
  v = (v | (v << 2)) & 0x3333u;
  v = (v | (v << 1)) & 0x5555u;
  return v;
}
static __device__ __forceinline__ int scellm(float x, float y) {
  int cx = (int)((x + 2.0f) * 16.0f); cx = min(SC - 1, max(0, cx));
  int cy = (int)((y + 2.0f) * 16.0f); cy = min(SC - 1, max(0, cy));
  return (int)(p1b1((unsigned)cx) | (p1b1((unsigned)cy) << 1));
}
static __device__ __forceinline__ int ccellm(float x, float y) {
  int cx = (int)(x * 16.0f); cx = min(15, max(0, cx));
  int cy = (int)(y * 16.0f); cy = min(15, max(0, cy));
  return (int)(p1b1((unsigned)cx) | (p1b1((unsigned)cy) << 1));
}

// ---------- shared prep body (callable by legacy prep kernel and block 0
// of the cooperative kernel). Works for blockDim 256 or 512. ----------
static __device__ void prep_body(
    const float* __restrict__ mu, const float* __restrict__ A,
    const float* __restrict__ w, float* __restrict__ C, int M, int psort) {
  __shared__ float red[512];
  __shared__ int uni[512];
  __shared__ int chist[256];
  __shared__ int coff[256];
  __shared__ float sMu0[2048];
  __shared__ float sMu1[2048];
  __shared__ float sWl[2048];
  const int t = threadIdx.x;
  const int BS = blockDim.x;
  const int NCL = M / CH;

  float mxv = -INFINITY;
  for (int m = t; m < M; m += BS) mxv = fmaxf(mxv, w[m]);
  red[t] = mxv; __syncthreads();
  for (int st = BS >> 1; st > 0; st >>= 1) {
    if (t < st) red[t] = fmaxf(red[t], red[t + st]);
    __syncthreads();
  }
  const float wmax = red[0]; __syncthreads();

  float sum = 0.f;
  for (int m = t; m < M; m += BS) sum += expf(w[m] - wmax);
  red[t] = sum; __syncthreads();
  for (int st = BS >> 1; st > 0; st >>= 1) {
    if (t < st) red[t] += red[t + st];
    __syncthreads();
  }
  const float logZ = wmax + logf(red[0]);
  __syncthreads();

  const float r00 = A[0], r01 = A[1], r10 = A[2], r11 = A[3];
  const float rg00 = 0.5f * (r00 * r00 + r01 * r01);
  const float rg01 = 0.5f * (r00 * r10 + r01 * r11);
  const float rg11 = 0.5f * (r10 * r10 + r11 * r11);

  if (t < 256) chist[t] = 0;
  __syncthreads();
  if (psort) {
    for (int m = t; m < M; m += BS)
      atomicAdd(&chist[ccellm(mu[m * 2 + 0], mu[m * 2 + 1])], 1);
  }
  __syncthreads();
  if (t == 0) {
    int acc = 0;
    for (int i = 0; i < 256; ++i) { int c = chist[i]; coff[i] = acc; acc += c; }
  }
  __syncthreads();

  const float LOG2E = 1.44269504088896340736f;
  int myuni = 1;
  for (int m = t; m < M; m += BS) {
    const float a00 = A[m * 4 + 0], a01 = A[m * 4 + 1];
    const float a10 = A[m * 4 + 2], a11 = A[m * 4 + 3];
    const float g00 = 0.5f * (a00 * a00 + a01 * a01);
    const float g01 = 0.5f * (a00 * a10 + a01 * a11);
    const float g11 = 0.5f * (a10 * a10 + a11 * a11);
    const float g01s = 2.0f * g01;
    const float det = g00 * g11 - g01 * g01;
    const float wlog = (w[m] - logZ) + 0.5f * logf(det);
    const float mu0 = mu[m * 2 + 0], mu1 = mu[m * 2 + 1];
    const float c0 = wlog - (g00 * mu0 * mu0 + g01s * mu0 * mu1 + g11 * mu1 * mu1);
    const float c2 = 2.0f * g00 * mu0 + g01s * mu1;
    const float c4 = 2.0f * g11 * mu1 + g01s * mu0;
    int slot = m;
    if (psort) {
      slot = atomicAdd(&coff[ccellm(mu0, mu1)], 1);
      sMu0[slot] = mu0; sMu1[slot] = mu1; sWl[slot] = LOG2E * wlog;
    }
    C[0 * M + slot] = LOG2E * c0;
    C[1 * M + slot] = LOG2E * -g00;
    C[2 * M + slot] = LOG2E * c2;
    C[3 * M + slot] = LOG2E * -g11;
    C[4 * M + slot] = LOG2E * c4;
    C[5 * M + slot] = LOG2E * -g01s;
    myuni &= (g00 == rg00) & (g01 == rg01) & (g11 == rg11);
  }
  uni[t] = myuni; __syncthreads();
  for (int st = BS >> 1; st > 0; st >>= 1) {
    if (t < st) uni[t] &= uni[t + st];
    __syncthreads();
  }

  // per-chunk meta: bbox center/radius, max & min wlog (log2 units)
  if (psort) {
    float* Mcx = C + 6 * M + 16;
    float* Mcy = Mcx + NCL;
    float* Mrx = Mcy + NCL;
    float* Mry = Mrx + NCL;
    float* MwX = Mry + NCL;
    float* MwN = MwX + NCL;
    for (int c = t; c < NCL; c += BS) {
      float mn0 = INFINITY, mx0 = -INFINITY, mn1 = INFINITY, mx1 = -INFINITY;
      float wx = -INFINITY, wn = INFINITY;
      for (int k = 0; k < CH; ++k) {
        const float u0 = sMu0[c * CH + k], u1 = sMu1[c * CH + k];
        mn0 = fminf(mn0, u0); mx0 = fmaxf(mx0, u0);
        mn1 = fminf(mn1, u1); mx1 = fmaxf(mx1, u1);
        wx = fmaxf(wx, sWl[c * CH + k]);
        wn = fminf(wn, sWl[c * CH + k]);
      }
      Mcx[c] = 0.5f * (mn0 + mx0); Mrx[c] = 0.5f * (mx0 - mn0);
      Mcy[c] = 0.5f * (mn1 + mx1); Mry[c] = 0.5f * (mx1 - mn1);
      MwX[c] = wx; MwN[c] = wn;
    }
  }

  if (t == 0) {
    ((int*)C)[6 * M + 0] = uni[0];
    C[6 * M + 1] = LOG2E * -rg00;        // cb1
    C[6 * M + 2] = LOG2E * -rg11;        // cb3
    C[6 * M + 3] = LOG2E * -2.0f * rg01; // cb5
    float tr = rg00 + rg11;
    float d0 = rg00 - rg11;
    float disc = sqrtf(d0 * d0 + 4.f * rg01 * rg01);
    float lam = 0.5f * (tr - disc);
    if (!(lam > 0.f)) lam = 0.f;
    C[6 * M + 4] = LOG2E * lam;          // lamL = log2e * lambda_min(G)
  }
}

__global__ __launch_bounds__(256) void prep_kernel(
    const float* __restrict__ mu, const float* __restrict__ A,
    const float* __restrict__ w, float* __restrict__ C, int M) {
  prep_body(mu, A, w, C, M, 0);
}

// process one chunk (CH comps) at plane offset MG; 2 samples/lane (v2f)
#define PROCESS2(MG) do {                                                    \
    v2f a_[CH];                                                              \
    _Pragma("unroll")                                                        \
    for (int j = 0; j < CH; ++j) {                                           \
      const float c0_ = Cp0[(MG) + j], c2_ = Cp2[(MG) + j],                  \
                  c4_ = Cp4[(MG) + j];                                       \
      v2f t_ = x0p * c2_ + c0_;                                              \
      a_[j] = x1p * c4_ + t_;                                                \
    }                                                                        \
    v2f t0_ = VMAX(a_[0], a_[1]);                                            \
    v2f t1_ = VMAX(a_[2], a_[3]);                                            \
    v2f t2_ = VMAX(a_[4], a_[5]);                                            \
    v2f t3_ = VMAX(a_[6], a_[7]);                                            \
    _Pragma("unroll")                                                        \
    for (int j = 8; j < CH; j += 4) {                                        \
      t0_ = VMAX(t0_, a_[j]);     t1_ = VMAX(t1_, a_[j + 1]);                \
      t2_ = VMAX(t2_, a_[j + 2]); t3_ = VMAX(t3_, a_[j + 3]);                \
    }                                                                        \
    const v2f cm_ = VMAX(VMAX(t0_, t1_), VMAX(t2_, t3_));                    \
    const v2f nm_ = VMAX(mx, cm_);                                           \
    v2f resc_;                                                               \
    resc_.x = EXP2(mx.x - nm_.x);                                            \
    resc_.y = EXP2(mx.y - nm_.y);                                            \
    const v2f knm_ = SCH_K2 - nm_ * SCH_K1;                                  \
    v2f l0_ = {0.f, 0.f}, l1_ = {0.f, 0.f};                                  \
    _Pragma("unroll")                                                        \
    for (int j = 0; j < CH; j += 2) {                                        \
      v2f u0_ = a_[j] * SCH_K1 + knm_;                                       \
      v2f u1_ = a_[j + 1] * SCH_K1 + knm_;                                   \
      u0_ = VMAX(u0_, tminv);                                                \
      u1_ = VMAX(u1_, tminv);                                                \
      const i2v iv0_ = __builtin_convertvector(u0_, i2v);                    \
      const i2v iv1_ = __builtin_convertvector(u1_, i2v);                    \
      l0_ += __builtin_bit_cast(v2f, iv0_);                                  \
      l1_ += __builtin_bit_cast(v2f, iv1_);                                  \
    }                                                                        \
    sacc = sacc * resc_ + (l0_ + l1_);                                       \
    mx = nm_;                                                                \
  } while (0)

// ---------------- the fused cooperative kernel ----------------
__global__ __launch_bounds__(512, 4) void gmix_coop(
    const float2* __restrict__ xsRaw, float2* __restrict__ ss,
    int* __restrict__ perm,
    const float* __restrict__ mu, const float* __restrict__ A,
    const float* __restrict__ w, float* __restrict__ C,
    int* __restrict__ histg, float* __restrict__ out,
    int N, int M, int BT) {
  cg::grid_group grid = cg::this_grid();
  __shared__ float Lmx[SPLIT][2][64];
  __shared__ float Lsm[SPLIT][2][64];
  __shared__ int part[256];
  __shared__ int sbt;

  const int tid = threadIdx.x;
  const int gtid = blockIdx.x * blockDim.x + tid;
  const int gstr = gridDim.x * blockDim.x;

  // phase 0: zero hist + tile counter (re-zeroed every graph replay)
  for (int i = gtid; i < SCELLS + 8; i += gstr) histg[i] = 0;
  __threadfence();
  grid.sync();

  // phase 1: sample histogram; block 0 also builds C (+ comp morton sort)
  for (int i = gtid; i < N; i += gstr) {
    const float2 p = xsRaw[i];
    atomicAdd(&histg[scellm(p.x, p.y)], 1);
  }
  if (blockIdx.x == 0) prep_body(mu, A, w, C, M, 1);
  __threadfence();
  grid.sync();

  // phase 2: exclusive scan (block 0)
  if (blockIdx.x == 0) {
    int v[16]; int lsum = 0;
    if (tid < 256) {
#pragma unroll
      for (int k = 0; k < 16; ++k) { v[k] = histg[tid * 16 + k]; lsum += v[k]; }
      part[tid] = lsum;
    }
    __syncthreads();
    if (tid == 0) {
      int acc = 0;
      for (int i = 0; i < 256; ++i) { int x = part[i]; part[i] = acc; acc += x; }
    }
    __syncthreads();
    if (tid < 256) {
      int acc = part[tid];
#pragma unroll
      for (int k = 0; k < 16; ++k) { int x = v[k]; histg[tid * 16 + k] = acc; acc += x; }
    }
  }
  __threadfence();
  grid.sync();

  // phase 3: scatter samples into morton-sorted order
  for (int i = gtid; i < N; i += gstr) {
    const float2 p = xsRaw[i];
    const int slot = atomicAdd(&histg[scellm(p.x, p.y)], 1);
    ss[slot] = p;
    perm[slot] = i;
  }
  __threadfence();
  grid.sync();

  // phase 4: compute, dynamic tiles of 128 samples
  const int lane = tid & 63;
  const int wave = __builtin_amdgcn_readfirstlane(tid >> 6);
  const int flag = ((const int*)C)[6 * M + 0];
  const float cb1 = C[6 * M + 1];
  const float cb3 = C[6 * M + 2];
  const float cb5 = C[6 * M + 3];
  const float lamL = C[6 * M + 4];
  const int NCL = M / CH;
  const float* __restrict__ Mcx = C + 6 * M + 16;
  const float* __restrict__ Mcy = Mcx + NCL;
  const float* __restrict__ Mrx = Mcy + NCL;
  const float* __restrict__ Mry = Mrx + NCL;
  const float* __restrict__ MwX = Mry + NCL;
  const float* __restrict__ MwN = MwX + NCL;
  const float* __restrict__ Cp0 = C;
  const float* __restrict__ Cp2 = C + 2 * M;
  const float* __restrict__ Cp4 = C + 4 * M;
  int* ctr = histg + SCELLS;
  const v2f tminv = {SCH_TMIN, SCH_TMIN};

  for (;;) {
    if (tid == 0) sbt = atomicAdd(ctr, 1);
    __syncthreads();                       // also guards Lmx reuse
    const int bt = sbt;
    if (bt >= BT) break;

    const int s0 = bt * 128 + lane;
    const int s1 = s0 + 64;
    const float2 z2 = make_float2(0.f, 0.f);
    const float2 pa = (s0 < N) ? ss[s0] : z2;
    const float2 pb = (s1 < N) ? ss[s1] : z2;
    const v2f x0p = {pa.x, pb.x};
    const v2f x1p = {pa.y, pb.y};
    v2f mx = {-INFINITY, -INFINITY};
    v2f sacc = {0.f, 0.f};
    v2f base = {0.f, 0.f};

    if (flag) {
      base = cb1 * x0p * x0p + cb3 * x1p * x1p + cb5 * x0p * x1p;

      // wave bbox (tight thanks to morton sort)
      float b0n = fminf(x0p.x, x0p.y), b0x = fmaxf(x0p.x, x0p.y);
      float b1n = fminf(x1p.x, x1p.y), b1x = fmaxf(x1p.x, x1p.y);
#pragma unroll
      for (int o = 32; o; o >>= 1) {
        b0n = fminf(b0n, __shfl_xor(b0n, o, 64));
        b0x = fmaxf(b0x, __shfl_xor(b0x, o, 64));
        b1n = fminf(b1n, __shfl_xor(b1n, o, 64));
        b1x = fmaxf(b1x, __shfl_xor(b1x, o, 64));
      }
      const float wcx = 0.5f * (b0n + b0x), wrx = 0.5f * (b0x - b0n);
      const float wcy = 0.5f * (b1n + b1x), wry = 0.5f * (b1x - b1n);

      // per-chunk near bound (ub) and lower-bound anchor anc0
      float ub[CPW];
      float anc = -INFINITY;
#pragma unroll
      for (int c = 0; c < CPW; ++c) {
        const int g = wave + SPLIT * c;
        const float ax = fabsf(wcx - Mcx[g]);
        const float ay = fabsf(wcy - Mcy[g]);
        const float rx = wrx + Mrx[g], ry = wry + Mry[g];
        const float nx = fmaxf(0.f, ax - rx), ny = fmaxf(0.f, ay - ry);
        const float fx = ax + rx, fy = ay + ry;
        ub[c] = MwX[g] - lamL * (nx * nx + ny * ny);
        anc = fmaxf(anc, MwN[g] - lamL * (fx * fx + fy * fy));
      }

      // best-first selection with early termination; the anc0-chunk always
      // has ub >= anc so at least one chunk is processed (S > 0)
      unsigned msk = 0;
      for (int it = 0; it < CPW; ++it) {
        float best = -INFINITY; int bi = -1;
#pragma unroll
        for (int c = 0; c < CPW; ++c)
          if (!((msk >> c) & 1u) && ub[c] > best) { best = ub[c]; bi = c; }
        if (bi < 0 || best < anc - T_SKIP) break;
        msk |= 1u << bi;
        const int sbi = __builtin_amdgcn_readfirstlane(bi);
        const int mg = (wave + SPLIT * sbi) * CH;
        PROCESS2(mg);
        v2f tt = mx + base;
        float am = fminf(tt.x, tt.y);
#pragma unroll
        for (int o = 32; o; o >>= 1) am = fminf(am, __shfl_xor(am, o, 64));
        anc = fmaxf(anc, am);
      }
    } else {
      // exact general path: all chunks, 6 coefs, hw exp2
      const int Mq = M / SPLIT;
      const int m0 = wave * Mq;
      const float* __restrict__ C0 = C + m0;
      const float* __restrict__ C1 = C + M + m0;
      const float* __restrict__ C2 = C + 2 * M + m0;
      const float* __restrict__ C3 = C + 3 * M + m0;
      const float* __restrict__ C4 = C + 4 * M + m0;
      const float* __restrict__ C5 = C + 5 * M + m0;
      for (int m = 0; m < Mq; m += CH) {
        v2f a[CH];
#pragma unroll
        for (int j = 0; j < CH; ++j) {
          const float c0 = C0[m + j], c1 = C1[m + j], c2 = C2[m + j];
          const float c3 = C3[m + j], c4 = C4[m + j], c5 = C5[m + j];
          v2f u = x0p * c1 + c2;
          u = x1p * c5 + u;
          v2f v = x1p * c3 + c4;
          v2f r = u * x0p + c0;
          a[j] = v * x1p + r;
        }
        v2f t0 = VMAX(a[0], a[1]);
        v2f t1 = VMAX(a[2], a[3]);
        v2f t2 = VMAX(a[4], a[5]);
        v2f t3 = VMAX(a[6], a[7]);
#pragma unroll
        for (int j = 8; j < CH; j += 4) {
          t0 = VMAX(t0, a[j]);     t1 = VMAX(t1, a[j + 1]);
          t2 = VMAX(t2, a[j + 2]); t3 = VMAX(t3, a[j + 3]);
        }
        const v2f cm = VMAX(VMAX(t0, t1), VMAX(t2, t3));
        const v2f nm = VMAX(mx, cm);
        v2f resc; resc.x = EXP2(mx.x - nm.x); resc.y = EXP2(mx.y - nm.y);
        v2f l0 = {0.f, 0.f}, l1 = {0.f, 0.f};
#pragma unroll
        for (int j = 0; j < CH; j += 2) {
          v2f d0 = a[j] - nm, d1 = a[j + 1] - nm;
          v2f e0, e1;
          e0.x = EXP2(d0.x); e0.y = EXP2(d0.y);
          e1.x = EXP2(d1.x); e1.y = EXP2(d1.y);
          l0 += e0; l1 += e1;
        }
        sacc = sacc * resc + (l0 + l1);
        mx = nm;
      }
    }

    // combine 8 waves (base folded into stored partial max)
#pragma unroll
    for (int k = 0; k < 2; ++k) {
      Lmx[wave][k][lane] = mx[k] + base[k];
      Lsm[wave][k][lane] = sacc[k];
    }
    __syncthreads();
    if (wave < 2) {
      const int slot = bt * 128 + wave * 64 + lane;
      if (slot < N) {
        float gm = Lmx[0][wave][lane];
#pragma unroll
        for (int v = 1; v < SPLIT; ++v) gm = fmaxf(gm, Lmx[v][wave][lane]);
        float S = 0.f;
#pragma unroll
        for (int v = 0; v < SPLIT; ++v)
          S += Lsm[v][wave][lane] * EXP2(Lmx[v][wave][lane] - gm);
        out[perm[slot]] = (gm + __log2f(S)) * 0.69314718055994530942f;
      }
    }
  }
}

// ---------------- legacy exact path (R9b) ----------------
__global__ __launch_bounds__(512, 4) void gmix_kernel(
    const float* __restrict__ sample,
    const float* __restrict__ C,
    float* __restrict__ out,
    int N, int M) {
  __shared__ float Lmx[SPLIT][4][64];
  __shared__ float Lsm[SPLIT][4][64];

  const int lane = threadIdx.x & 63;
  const int wave = __builtin_amdgcn_readfirstlane((int)(threadIdx.x >> 6));
  const int n0 = blockIdx.x * 256 + lane;

  float2 xs0 = (n0       < N) ? ((const float2*)sample)[n0      ] : make_float2(0.f, 0.f);
  float2 xs1 = (n0 + 64  < N) ? ((const float2*)sample)[n0 + 64 ] : make_float2(0.f, 0.f);
  float2 xs2 = (n0 + 128 < N) ? ((const float2*)sample)[n0 + 128] : make_float2(0.f, 0.f);
  float2 xs3 = (n0 + 192 < N) ? ((const float2*)sample)[n0 + 192] : make_float2(0.f, 0.f);
  const v4f x0q = {xs0.x, xs1.x, xs2.x, xs3.x};
  const v4f x1q = {xs0.y, xs1.y, xs2.y, xs3.y};

  const int flag = ((const int*)C)[6 * M + 0];
  const float cb1 = C[6 * M + 1];
  const float cb3 = C[6 * M + 2];
  const float cb5 = C[6 * M + 3];

  const int Mq = M / SPLIT;
  const int m0 = wave * Mq;
  const float* __restrict__ C0 = C + m0;
  const float* __restrict__ C1 = C + M + m0;
  const float* __restrict__ C2 = C + 2 * M + m0;
  const float* __restrict__ C3 = C + 3 * M + m0;
  const float* __restrict__ C4 = C + 4 * M + m0;
  const float* __restrict__ C5 = C + 5 * M + m0;

  v4f base4 = {0.f, 0.f, 0.f, 0.f};
  v4f mx = {-INFINITY, -INFINITY, -INFINITY, -INFINITY};
  v4f s  = {0.f, 0.f, 0.f, 0.f};
  const v4f tminv4 = {SCH_TMIN, SCH_TMIN, SCH_TMIN, SCH_TMIN};

  if (flag) {
    base4 = cb1 * x0q * x0q + cb3 * x1q * x1q + cb5 * x0q * x1q;
    for (int m = 0; m < Mq; m += CH) {
      v4f a[CH];
#pragma unroll
      for (int j = 0; j < CH; ++j) {
        const float c0 = C0[m + j], c2 = C2[m + j], c4 = C4[m + j];
        v4f t = x0q * c2 + c0;
        a[j] = x1q * c4 + t;
      }
      v4f t0 = VMAX(a[0], a[1]);
      v4f t1 = VMAX(a[2], a[3]);
      v4f t2 = VMAX(a[4], a[5]);
      v4f t3 = VMAX(a[6], a[7]);
#pragma unroll
      for (int j = 8; j < CH; j += 4) {
        t0 = VMAX(t0, a[j]);     t1 = VMAX(t1, a[j + 1]);
        t2 = VMAX(t2, a[j + 2]); t3 = VMAX(t3, a[j + 3]);
      }
      const v4f cm = VMAX(VMAX(t0, t1), VMAX(t2, t3));
      const v4f nm = VMAX(mx, cm);
      v4f resc;
      resc.x = EXP2(mx.x - nm.x); resc.y = EXP2(mx.y - nm.y);
      resc.z = EXP2(mx.z - nm.z); resc.w = EXP2(mx.w - nm.w);
      const v4f knm = SCH_K2 - nm * SCH_K1;
      v4f l0 = {0.f, 0.f, 0.f, 0.f}, l1 = {0.f, 0.f, 0.f, 0.f};
#pragma unroll
      for (int j = 0; j < CH; j += 2) {
        v4f u0 = a[j]     * SCH_K1 + knm;
        v4f u1 = a[j + 1] * SCH_K1 + knm;
        u0 = VMAX(u0, tminv4);
        u1 = VMAX(u1, tminv4);
        const i4v iv0 = __builtin_convertvector(u0, i4v);
        const i4v iv1 = __builtin_convertvector(u1, i4v);
        l0 += __builtin_bit_cast(v4f, iv0);
        l1 += __builtin_bit_cast(v4f, iv1);
      }
      s = s * resc + (l0 + l1);
      mx = nm;
    }
  } else {
    for (int m = 0; m < Mq; m += CH) {
      v4f a[CH];
#pragma unroll
      for (int j = 0; j < CH; ++j) {
        const float c0 = C0[m + j], c1 = C1[m + j], c2 = C2[m + j];
        const float c3 = C3[m + j], c4 = C4[m + j], c5 = C5[m + j];
        v4f u = x0q * c1 + c2;
        u = x1q * c5 + u;
        v4f v = x1q * c3 + c4;
        v4f r = u * x0q + c0;
        a[j] = v * x1q + r;
      }
      v4f t0 = VMAX(a[0], a[1]);
      v4f t1 = VMAX(a[2], a[3]);
      v4f t2 = VMAX(a[4], a[5]);
      v4f t3 = VMAX(a[6], a[7]);
#pragma unroll
      for (int j = 8; j < CH; j += 4) {
        t0 = VMAX(t0, a[j]);     t1 = VMAX(t1, a[j + 1]);
        t2 = VMAX(t2, a[j + 2]); t3 = VMAX(t3, a[j + 3]);
      }
      const v4f cm = VMAX(VMAX(t0, t1), VMAX(t2, t3));
      const v4f nm = VMAX(mx, cm);
      v4f resc;
      resc.x = EXP2(mx.x - nm.x); resc.y = EXP2(mx.y - nm.y);
      resc.z = EXP2(mx.z - nm.z); resc.w = EXP2(mx.w - nm.w);
      v4f l0 = {0.f, 0.f, 0.f, 0.f}, l1 = {0.f, 0.f, 0.f, 0.f};
#pragma unroll
      for (int j = 0; j < CH; j += 2) {
        v4f d0 = a[j] - nm, d1 = a[j + 1] - nm;
        v4f e0, e1;
        e0.x = EXP2(d0.x); e0.y = EXP2(d0.y); e0.z = EXP2(d0.z); e0.w = EXP2(d0.w);
        e1.x = EXP2(d1.x); e1.y = EXP2(d1.y); e1.z = EXP2(d1.z); e1.w = EXP2(d1.w);
        l0 += e0; l1 += e1;
      }
      s = s * resc + (l0 + l1);
      mx = nm;
    }
  }

#pragma unroll
  for (int k = 0; k < 4; ++k) {
    Lmx[wave][k][lane] = mx[k] + base4[k];
    Lsm[wave][k][lane] = s[k];
  }
  __syncthreads();

  if (wave < 4) {
    const int set = wave;
    const int n = blockIdx.x * 256 + set * 64 + lane;
    if (n < N) {
      float gm = Lmx[0][set][lane];
#pragma unroll
      for (int v = 1; v < SPLIT; ++v) gm = fmaxf(gm, Lmx[v][set][lane]);
      float S = 0.f;
#pragma unroll
      for (int v = 0; v < SPLIT; ++v)
        S += Lsm[v][set][lane] * EXP2(Lmx[v][set][lane] - gm);
      out[n] = (gm + __log2f(S)) * 0.69314718055994530942f;
    }
  }
}

extern "C" void kernel_launch(void* const* d_in, const int* in_sizes, int n_in,
                              void* d_out, int out_size, void* d_ws, size_t ws_size,
                              hipStream_t stream) {
  const float* sample = (const float*)d_in[0];
  const float* mu     = (const float*)d_in[1];
  const float* A      = (const float*)d_in[2];
  const float* w      = (const float*)d_in[3];
  float* out = (float*)d_out;

  const int N = in_sizes[0] / 2;   // sample is (N,2)
  const int M = in_sizes[3];       // w is (M,1)

  float* C = (float*)d_ws;
  const int NCc = (M / CH > 0) ? M / CH : 1;
  const size_t cBytes  = ((size_t)6 * M + 16 + 6 * (size_t)NCc) * 4;
  const size_t offHist = (cBytes + 255) & ~(size_t)255;
  const size_t offSS   = (offHist + (size_t)(SCELLS + 8) * 4 + 255) & ~(size_t)255;
  const size_t offPerm = (offSS + (size_t)N * 8 + 255) & ~(size_t)255;
  const size_t need    = offPerm + (size_t)N * 4;

  static int s_coop = -2;   // -2 = unqueried; <=0 = unusable
  if (s_coop == -2) {
    int nb = 0, ncu = 0, dev = 0;
    (void)hipGetDevice(&dev);
    if (hipOccupancyMaxActiveBlocksPerMultiprocessor(
            &nb, (const void*)gmix_coop, 512, 0) != hipSuccess) nb = 0;
    if (hipDeviceGetAttribute(&ncu, hipDeviceAttributeMultiprocessorCount,
                              dev) != hipSuccess) ncu = 0;
    s_coop = nb * ncu;
  }

  const bool coopEn = (s_coop > 0) && (ws_size >= need) && (M == 2048) && (N >= 1);

  if (coopEn) {
    int* histg   = (int*)((char*)d_ws + offHist);
    float2* ssp  = (float2*)((char*)d_ws + offSS);
    int* permp   = (int*)((char*)d_ws + offPerm);
    int BT = (N + 127) / 128;
    int G = s_coop; if (G > BT) G = BT; if (G > 2048) G = 2048; if (G < 1) G = 1;
    const float2* xr = (const float2*)sample;
    int Nv = N, Mv = M, BTv = BT;
    void* kargs[] = {(void*)&xr, (void*)&ssp, (void*)&permp,
                     (void*)&mu, (void*)&A, (void*)&w, (void*)&C,
                     (void*)&histg, (void*)&out,
                     (void*)&Nv, (void*)&Mv, (void*)&BTv};
    (void)hipLaunchCooperativeKernel((const void*)gmix_coop, dim3(G), dim3(512),
                                     kargs, 0, stream);
  } else {
    prep_kernel<<<1, 256, 0, stream>>>(mu, A, w, C, M);
    gmix_kernel<<<(N + 255) / 256, 512, 0, stream>>>(sample, C, out, N, M);
  }
}

// Round 7
// 114.665 us; speedup vs baseline: 3.9111x; 3.9111x over previous
//
#include <hip/hip_runtime.h>
#include <math.h>

// GaussianMixture log-likelihood: ll[n] = logsumexp_m( wlog[m] - dx^T G_m dx )
// R12: MFMA path. R11 post-mortem: coop fusion = 448us disaster (grid.sync
// spin at 3% VALUBusy); pruning needs sorts/dispatches that cost more than
// they save. R6-R9 proved the VALU loop is issue-bound at ~7 ops/comp and
// schedule-invariant. Untapped resource: matrix pipe (MfmaUtil 0%).
// arg(n,m) = c0_m + c2_m*x0_n + c4_m*x1_n is a rank-3 matmul ->
// mfma_f32_16x16x32_bf16 with hi/lo bf16 splitting:
//   A k-slots (per sample): [x0h,x0l,x0h,x1h,x1l,x1h,1,1]  (lanes 16-63 = 0)
//   B k-slots (per comp):   [c2h,c2h,c2l,c4h,c4h,c4l,c0h,c0l]
// dot = c2*(x0h+x0l) + c2l*x0h + c4*(x1h+x1l) + c4l*x1h + c0h+c0l
// arg err ~0.035 log2 (~2.4%) -- same class as Schraudolph 3% (passed, 4.0).
// D layout (m89, verified): col=lane&15 (comp), row=(lane>>4)*4+j (sample).
// VALU keeps only the epilogue: per 8-MFMA batch per row: complete max tree
// (R5 NaN lesson), 1 rescale, 8x {fma K1, clamp, cvt, add} ~5.3 ops/arg.
// Cross-lane merge over the 16 comp-lanes via shfl_xor; base folded at end.
// flag==0 (non-uniform G) -> exact R7 general path (same 128-sample blocks).
// ws too small / M%128 -> legacy R9b kernel (exact fallback).

#if __has_builtin(__builtin_amdgcn_exp2f)
#define EXP2(x) __builtin_amdgcn_exp2f(x)
#else
#define EXP2(x) exp2f(x)
#endif

typedef float v2f   __attribute__((ext_vector_type(2)));
typedef float f32x4 __attribute__((ext_vector_type(4)));
typedef short bf16x8 __attribute__((ext_vector_type(8)));
typedef float v4f __attribute__((ext_vector_type(4)));
typedef int   i4v __attribute__((ext_vector_type(4)));

#if __has_builtin(__builtin_elementwise_max)
#define VMAX(a, b) __builtin_elementwise_max(a, b)
#else
static __device__ inline v2f VMAX(v2f a, v2f b) {
  v2f r; r.x = fmaxf(a.x, b.x); r.y = fmaxf(a.y, b.y); return r;
}
static __device__ inline v4f VMAX(v4f a, v4f b) {
  v4f r; r.x = fmaxf(a.x, b.x); r.y = fmaxf(a.y, b.y);
  r.z = fmaxf(a.z, b.z); r.w = fmaxf(a.w, b.w); return r;
}
#endif

// Schraudolph exp2 (fp32): y = bitcast(int(x*2^23 + 127*2^23 - C)), C=366393
#define SCH_K1   8388608.0f
#define SCH_K2   1064986823.0f
#define SCH_TMIN 58353856.0f     // clamp keeps cvt/bitcast valid

#define SPLIT 8
#define CH  16
#define RMF 8                    // MFMAs per epilogue batch
#define LOG2E 1.44269504088896340736f
#define LN2   0.69314718055994530942f

__device__ __forceinline__ unsigned short f2bf(float f) {
  unsigned u = __builtin_bit_cast(unsigned, f);
  unsigned r = u + 0x7FFFu + ((u >> 16) & 1u);   // RNE
  return (unsigned short)(r >> 16);
}
__device__ __forceinline__ float bf2f(unsigned short h) {
  unsigned u = ((unsigned)h) << 16;
  return __builtin_bit_cast(float, u);
}

// ---------------- prep: coefficients + bf16-packed B fragments ----------------
__global__ __launch_bounds__(256) void prep_kernel(
    const float* __restrict__ mu,
    const float* __restrict__ A,
    const float* __restrict__ w,
    float* __restrict__ C,   // [6][M] planes + header + Bpack[M][8] bf16
    int M) {
  __shared__ float red[256];
  __shared__ int uni[256];
  const int t = threadIdx.x;

  float mx = -INFINITY;
  for (int m = t; m < M; m += 256) mx = fmaxf(mx, w[m]);
  red[t] = mx; __syncthreads();
  for (int s = 128; s > 0; s >>= 1) {
    if (t < s) red[t] = fmaxf(red[t], red[t + s]);
    __syncthreads();
  }
  const float wmax = red[0]; __syncthreads();

  float sum = 0.f;
  for (int m = t; m < M; m += 256) sum += expf(w[m] - wmax);
  red[t] = sum; __syncthreads();
  for (int s = 128; s > 0; s >>= 1) {
    if (t < s) red[t] += red[t + s];
    __syncthreads();
  }
  const float logZ = wmax + logf(red[0]);

  const float r00 = A[0], r01 = A[1], r10 = A[2], r11 = A[3];
  const float rg00 = 0.5f * (r00 * r00 + r01 * r01);
  const float rg01 = 0.5f * (r00 * r10 + r01 * r11);
  const float rg11 = 0.5f * (r10 * r10 + r11 * r11);

  unsigned short* Bp = (unsigned short*)(C + 6 * M + 16);

  int myuni = 1;
  for (int m = t; m < M; m += 256) {
    const float a00 = A[m * 4 + 0], a01 = A[m * 4 + 1];
    const float a10 = A[m * 4 + 2], a11 = A[m * 4 + 3];
    const float g00 = 0.5f * (a00 * a00 + a01 * a01);
    const float g01 = 0.5f * (a00 * a10 + a01 * a11);
    const float g11 = 0.5f * (a10 * a10 + a11 * a11);
    const float g01s = 2.0f * g01;
    const float det = g00 * g11 - g01 * g01;
    const float wlog = (w[m] - logZ) + 0.5f * logf(det);
    const float mu0 = mu[m * 2 + 0], mu1 = mu[m * 2 + 1];
    const float c0 = wlog - (g00 * mu0 * mu0 + g01s * mu0 * mu1 + g11 * mu1 * mu1);
    const float c2 = 2.0f * g00 * mu0 + g01s * mu1;
    const float c4 = 2.0f * g11 * mu1 + g01s * mu0;
    const float C0v = LOG2E * c0;
    const float C2v = LOG2E * c2;
    const float C4v = LOG2E * c4;
    C[0 * M + m] = C0v;
    C[1 * M + m] = LOG2E * -g00;
    C[2 * M + m] = C2v;
    C[3 * M + m] = LOG2E * -g11;
    C[4 * M + m] = C4v;
    C[5 * M + m] = LOG2E * -g01s;
    // bf16 hi/lo packing for the MFMA B-fragment
    const unsigned short c2h = f2bf(C2v);
    const unsigned short c2l = f2bf(C2v - bf2f(c2h));
    const unsigned short c4h = f2bf(C4v);
    const unsigned short c4l = f2bf(C4v - bf2f(c4h));
    const unsigned short c0h = f2bf(C0v);
    const unsigned short c0l = f2bf(C0v - bf2f(c0h));
    Bp[m * 8 + 0] = c2h; Bp[m * 8 + 1] = c2h; Bp[m * 8 + 2] = c2l;
    Bp[m * 8 + 3] = c4h; Bp[m * 8 + 4] = c4h; Bp[m * 8 + 5] = c4l;
    Bp[m * 8 + 6] = c0h; Bp[m * 8 + 7] = c0l;
    myuni &= (g00 == rg00) & (g01 == rg01) & (g11 == rg11);
  }
  uni[t] = myuni; __syncthreads();
  for (int s = 128; s > 0; s >>= 1) {
    if (t < s) uni[t] &= uni[t + s];
    __syncthreads();
  }
  if (t == 0) {
    ((int*)C)[6 * M + 0] = uni[0];
    C[6 * M + 1] = LOG2E * -rg00;        // cb1
    C[6 * M + 2] = LOG2E * -rg11;        // cb3
    C[6 * M + 3] = LOG2E * -2.0f * rg01; // cb5
  }
}

// epilogue for one sample-row j over an 8-MFMA batch (complete max tree)
#define EPI(J, MXJ, SJ) do {                                                 \
    const float a0 = acc[0][J], a1 = acc[1][J], a2 = acc[2][J],              \
                a3 = acc[3][J], a4 = acc[4][J], a5 = acc[5][J],              \
                a6 = acc[6][J], a7 = acc[7][J];                              \
    const float m01 = fmaxf(a0, a1), m23 = fmaxf(a2, a3);                    \
    const float m45 = fmaxf(a4, a5), m67 = fmaxf(a6, a7);                    \
    const float cm = fmaxf(fmaxf(m01, m23), fmaxf(m45, m67));                \
    const float nm = fmaxf(MXJ, cm);                                         \
    const float resc = EXP2(MXJ - nm);                                       \
    const float knm = fmaf(nm, -SCH_K1, SCH_K2);                             \
    const float e0 = __builtin_bit_cast(float, (int)fmaxf(fmaf(a0, SCH_K1, knm), SCH_TMIN)); \
    const float e1 = __builtin_bit_cast(float, (int)fmaxf(fmaf(a1, SCH_K1, knm), SCH_TMIN)); \
    const float e2 = __builtin_bit_cast(float, (int)fmaxf(fmaf(a2, SCH_K1, knm), SCH_TMIN)); \
    const float e3 = __builtin_bit_cast(float, (int)fmaxf(fmaf(a3, SCH_K1, knm), SCH_TMIN)); \
    const float e4 = __builtin_bit_cast(float, (int)fmaxf(fmaf(a4, SCH_K1, knm), SCH_TMIN)); \
    const float e5 = __builtin_bit_cast(float, (int)fmaxf(fmaf(a5, SCH_K1, knm), SCH_TMIN)); \
    const float e6 = __builtin_bit_cast(float, (int)fmaxf(fmaf(a6, SCH_K1, knm), SCH_TMIN)); \
    const float e7 = __builtin_bit_cast(float, (int)fmaxf(fmaf(a7, SCH_K1, knm), SCH_TMIN)); \
    const float sm = ((e0 + e1) + (e2 + e3)) + ((e4 + e5) + (e6 + e7));      \
    SJ = fmaf(SJ, resc, sm);                                                 \
    MXJ = nm;                                                                \
  } while (0)

#define MERGE(MXJ, SJ, OFF) do {                                             \
    const float om = __shfl_xor(MXJ, OFF, 64);                               \
    const float os = __shfl_xor(SJ, OFF, 64);                                \
    const float nm = fmaxf(MXJ, om);                                         \
    SJ = SJ * EXP2(MXJ - nm) + os * EXP2(om - nm);                           \
    MXJ = nm;                                                                \
  } while (0)

// grid: (N+127)/128 blocks x 512 threads; wave w owns samples blk*128+w*16+[0,16)
__global__ __launch_bounds__(512, 3) void gmix_mfma(
    const float2* __restrict__ xs,
    const float* __restrict__ C,
    float* __restrict__ out,
    int N, int M) {
  __shared__ float Lmx[SPLIT][2][64];
  __shared__ float Lsm[SPLIT][2][64];
  const int lane = threadIdx.x & 63;
  const int wave = __builtin_amdgcn_readfirstlane((int)(threadIdx.x >> 6));
  const int flag = ((const int*)C)[6 * M + 0];
  const float cb1 = C[6 * M + 1];
  const float cb3 = C[6 * M + 2];
  const float cb5 = C[6 * M + 3];

  if (flag) {
    const bf16x8* __restrict__ Bv = (const bf16x8*)(C + 6 * M + 16);
    const int sbase = blockIdx.x * 128 + wave * 16;
    const int col = lane & 15;

    // A fragment: lanes 0-15 carry sample features at k=0..7; others zero
    // (B is loaded unmasked into k>=8 slots -- harmless, A is 0 there).
    const int sA = sbase + col;
    const float2 xa = (sA < N) ? xs[sA] : make_float2(0.f, 0.f);
    bf16x8 afrag = (bf16x8){0, 0, 0, 0, 0, 0, 0, 0};
    if (lane < 16) {
      const unsigned short x0h = f2bf(xa.x);
      const unsigned short x0l = f2bf(xa.x - bf2f(x0h));
      const unsigned short x1h = f2bf(xa.y);
      const unsigned short x1l = f2bf(xa.y - bf2f(x1h));
      afrag = (bf16x8){(short)x0h, (short)x0l, (short)x0h,
                       (short)x1h, (short)x1l, (short)x1h,
                       (short)0x3F80, (short)0x3F80};   // 1.0bf16 x2 (c0h,c0l)
    }

    float mx0 = -INFINITY, mx1 = -INFINITY, mx2 = -INFINITY, mx3 = -INFINITY;
    float s0 = 0.f, s1 = 0.f, s2 = 0.f, s3 = 0.f;
    const f32x4 z4 = {0.f, 0.f, 0.f, 0.f};
    const int rounds = M / (RMF * 16);

#pragma unroll 2
    for (int t = 0; t < rounds; ++t) {
      f32x4 acc[RMF];
#pragma unroll
      for (int r = 0; r < RMF; ++r) {
        const bf16x8 bfrag = Bv[t * (RMF * 16) + r * 16 + col];
        acc[r] = __builtin_amdgcn_mfma_f32_16x16x32_bf16(afrag, bfrag, z4, 0, 0, 0);
      }
      EPI(0, mx0, s0);
      EPI(1, mx1, s1);
      EPI(2, mx2, s2);
      EPI(3, mx3, s3);
    }

    // merge across the 16 comp-lanes of each row group
#pragma unroll
    for (int off = 1; off < 16; off <<= 1) {
      MERGE(mx0, s0, off);
      MERGE(mx1, s1, off);
      MERGE(mx2, s2, off);
      MERGE(mx3, s3, off);
    }

    if (col == 0) {
      const int g = lane >> 4;
#define OUTJ(J, MXJ, SJ) do {                                                \
        const int sr = sbase + g * 4 + (J);                                  \
        if (sr < N) {                                                        \
          const float2 xo = xs[sr];                                          \
          const float base = cb1 * xo.x * xo.x + cb3 * xo.y * xo.y +         \
                             cb5 * xo.x * xo.y;                              \
          out[sr] = (MXJ + base + __log2f(SJ)) * LN2;                        \
        }                                                                    \
      } while (0)
      OUTJ(0, mx0, s0);
      OUTJ(1, mx1, s1);
      OUTJ(2, mx2, s2);
      OUTJ(3, mx3, s3);
#undef OUTJ
    }
  } else {
    // exact general path (R7): 128 samples/block, 8-wave M-split, v2f, hw exp2
    const int nA = blockIdx.x * 128 + lane;
    const int nB = nA + 64;
    const float2 xA = (nA < N) ? xs[nA] : make_float2(0.f, 0.f);
    const float2 xB = (nB < N) ? xs[nB] : make_float2(0.f, 0.f);
    const v2f x0p = {xA.x, xB.x};
    const v2f x1p = {xA.y, xB.y};

    const int Mq = M / SPLIT;
    const int m0 = wave * Mq;
    const float* __restrict__ C0 = C + m0;
    const float* __restrict__ C1 = C + M + m0;
    const float* __restrict__ C2 = C + 2 * M + m0;
    const float* __restrict__ C3 = C + 3 * M + m0;
    const float* __restrict__ C4 = C + 4 * M + m0;
    const float* __restrict__ C5 = C + 5 * M + m0;

    v2f mx = {-INFINITY, -INFINITY};
    v2f sacc = {0.f, 0.f};
    for (int m = 0; m < Mq; m += CH) {
      v2f a[CH];
#pragma unroll
      for (int j = 0; j < CH; ++j) {
        const float c0 = C0[m + j], c1 = C1[m + j], c2 = C2[m + j];
        const float c3 = C3[m + j], c4 = C4[m + j], c5 = C5[m + j];
        v2f u = x0p * c1 + c2;
        u = x1p * c5 + u;
        v2f v = x1p * c3 + c4;
        v2f r = u * x0p + c0;
        a[j] = v * x1p + r;
      }
      v2f t0 = VMAX(a[0], a[1]);
      v2f t1 = VMAX(a[2], a[3]);
      v2f t2 = VMAX(a[4], a[5]);
      v2f t3 = VMAX(a[6], a[7]);
#pragma unroll
      for (int j = 8; j < CH; j += 4) {
        t0 = VMAX(t0, a[j]);     t1 = VMAX(t1, a[j + 1]);
        t2 = VMAX(t2, a[j + 2]); t3 = VMAX(t3, a[j + 3]);
      }
      const v2f cm = VMAX(VMAX(t0, t1), VMAX(t2, t3));
      const v2f nm = VMAX(mx, cm);
      v2f resc; resc.x = EXP2(mx.x - nm.x); resc.y = EXP2(mx.y - nm.y);
      v2f l0 = {0.f, 0.f}, l1 = {0.f, 0.f};
#pragma unroll
      for (int j = 0; j < CH; j += 2) {
        const v2f d0 = a[j] - nm, d1 = a[j + 1] - nm;
        v2f e0, e1;
        e0.x = EXP2(d0.x); e0.y = EXP2(d0.y);
        e1.x = EXP2(d1.x); e1.y = EXP2(d1.y);
        l0 += e0; l1 += e1;
      }
      sacc = sacc * resc + (l0 + l1);
      mx = nm;
    }
    // fold base into partial max; combine waves via LDS
    const v2f base = cb1 * x0p * x0p + cb3 * x1p * x1p + cb5 * x0p * x1p;
#pragma unroll
    for (int k = 0; k < 2; ++k) {
      Lmx[wave][k][lane] = mx[k] + base[k];
      Lsm[wave][k][lane] = sacc[k];
    }
    __syncthreads();
    if (wave < 2) {
      const int n = blockIdx.x * 128 + wave * 64 + lane;
      if (n < N) {
        float gm = Lmx[0][wave][lane];
#pragma unroll
        for (int v = 1; v < SPLIT; ++v) gm = fmaxf(gm, Lmx[v][wave][lane]);
        float S = 0.f;
#pragma unroll
        for (int v = 0; v < SPLIT; ++v)
          S += Lsm[v][wave][lane] * EXP2(Lmx[v][wave][lane] - gm);
        out[n] = (gm + __log2f(S)) * LN2;
      }
    }
  }
}

// ---------------- legacy exact fallback (R9b structure) ----------------
__global__ __launch_bounds__(512, 4) void gmix_kernel(
    const float* __restrict__ sample,
    const float* __restrict__ C,
    float* __restrict__ out,
    int N, int M) {
  __shared__ float Lmx[SPLIT][4][64];
  __shared__ float Lsm[SPLIT][4][64];

  const int lane = threadIdx.x & 63;
  const int wave = __builtin_amdgcn_readfirstlane((int)(threadIdx.x >> 6));
  const int n0 = blockIdx.x * 256 + lane;

  float2 xs0 = (n0       < N) ? ((const float2*)sample)[n0      ] : make_float2(0.f, 0.f);
  float2 xs1 = (n0 + 64  < N) ? ((const float2*)sample)[n0 + 64 ] : make_float2(0.f, 0.f);
  float2 xs2 = (n0 + 128 < N) ? ((const float2*)sample)[n0 + 128] : make_float2(0.f, 0.f);
  float2 xs3 = (n0 + 192 < N) ? ((const float2*)sample)[n0 + 192] : make_float2(0.f, 0.f);
  const v4f x0q = {xs0.x, xs1.x, xs2.x, xs3.x};
  const v4f x1q = {xs0.y, xs1.y, xs2.y, xs3.y};

  const int flag = ((const int*)C)[6 * M + 0];
  const float cb1 = C[6 * M + 1];
  const float cb3 = C[6 * M + 2];
  const float cb5 = C[6 * M + 3];

  const int Mq = M / SPLIT;
  const int m0 = wave * Mq;
  const float* __restrict__ C0 = C + m0;
  const float* __restrict__ C1 = C + M + m0;
  const float* __restrict__ C2 = C + 2 * M + m0;
  const float* __restrict__ C3 = C + 3 * M + m0;
  const float* __restrict__ C4 = C + 4 * M + m0;
  const float* __restrict__ C5 = C + 5 * M + m0;

  v4f base4 = {0.f, 0.f, 0.f, 0.f};
  v4f mx = {-INFINITY, -INFINITY, -INFINITY, -INFINITY};
  v4f s  = {0.f, 0.f, 0.f, 0.f};
  const v4f tminv4 = {SCH_TMIN, SCH_TMIN, SCH_TMIN, SCH_TMIN};

  if (flag) {
    base4 = cb1 * x0q * x0q + cb3 * x1q * x1q + cb5 * x0q * x1q;
    for (int m = 0; m < Mq; m += CH) {
      v4f a[CH];
#pragma unroll
      for (int j = 0; j < CH; ++j) {
        const float c0 = C0[m + j], c2 = C2[m + j], c4 = C4[m + j];
        v4f t = x0q * c2 + c0;
        a[j] = x1q * c4 + t;
      }
      v4f t0 = VMAX(a[0], a[1]);
      v4f t1 = VMAX(a[2], a[3]);
      v4f t2 = VMAX(a[4], a[5]);
      v4f t3 = VMAX(a[6], a[7]);
#pragma unroll
      for (int j = 8; j < CH; j += 4) {
        t0 = VMAX(t0, a[j]);     t1 = VMAX(t1, a[j + 1]);
        t2 = VMAX(t2, a[j + 2]); t3 = VMAX(t3, a[j + 3]);
      }
      const v4f cm = VMAX(VMAX(t0, t1), VMAX(t2, t3));
      const v4f nm = VMAX(mx, cm);
      v4f resc;
      resc.x = EXP2(mx.x - nm.x); resc.y = EXP2(mx.y - nm.y);
      resc.z = EXP2(mx.z - nm.z); resc.w = EXP2(mx.w - nm.w);
      const v4f knm = SCH_K2 - nm * SCH_K1;
      v4f l0 = {0.f, 0.f, 0.f, 0.f}, l1 = {0.f, 0.f, 0.f, 0.f};
#pragma unroll
      for (int j = 0; j < CH; j += 2) {
        v4f u0 = a[j]     * SCH_K1 + knm;
        v4f u1 = a[j + 1] * SCH_K1 + knm;
        u0 = VMAX(u0, tminv4);
        u1 = VMAX(u1, tminv4);
        const i4v iv0 = __builtin_convertvector(u0, i4v);
        const i4v iv1 = __builtin_convertvector(u1, i4v);
        l0 += __builtin_bit_cast(v4f, iv0);
        l1 += __builtin_bit_cast(v4f, iv1);
      }
      s = s * resc + (l0 + l1);
      mx = nm;
    }
  } else {
    for (int m = 0; m < Mq; m += CH) {
      v4f a[CH];
#pragma unroll
      for (int j = 0; j < CH; ++j) {
        const float c0 = C0[m + j], c1 = C1[m + j], c2 = C2[m + j];
        const float c3 = C3[m + j], c4 = C4[m + j], c5 = C5[m + j];
        v4f u = x0q * c1 + c2;
        u = x1q * c5 + u;
        v4f v = x1q * c3 + c4;
        v4f r = u * x0q + c0;
        a[j] = v * x1q + r;
      }
      v4f t0 = VMAX(a[0], a[1]);
      v4f t1 = VMAX(a[2], a[3]);
      v4f t2 = VMAX(a[4], a[5]);
      v4f t3 = VMAX(a[6], a[7]);
#pragma unroll
      for (int j = 8; j < CH; j += 4) {
        t0 = VMAX(t0, a[j]);     t1 = VMAX(t1, a[j + 1]);
        t2 = VMAX(t2, a[j + 2]); t3 = VMAX(t3, a[j + 3]);
      }
      const v4f cm = VMAX(VMAX(t0, t1), VMAX(t2, t3));
      const v4f nm = VMAX(mx, cm);
      v4f resc;
      resc.x = EXP2(mx.x - nm.x); resc.y = EXP2(mx.y - nm.y);
      resc.z = EXP2(mx.z - nm.z); resc.w = EXP2(mx.w - nm.w);
      v4f l0 = {0.f, 0.f, 0.f, 0.f}, l1 = {0.f, 0.f, 0.f, 0.f};
#pragma unroll
      for (int j = 0; j < CH; j += 2) {
        v4f d0 = a[j] - nm, d1 = a[j + 1] - nm;
        v4f e0, e1;
        e0.x = EXP2(d0.x); e0.y = EXP2(d0.y); e0.z = EXP2(d0.z); e0.w = EXP2(d0.w);
        e1.x = EXP2(d1.x); e1.y = EXP2(d1.y); e1.z = EXP2(d1.z); e1.w = EXP2(d1.w);
        l0 += e0; l1 += e1;
      }
      s = s * resc + (l0 + l1);
      mx = nm;
    }
  }

#pragma unroll
  for (int k = 0; k < 4; ++k) {
    Lmx[wave][k][lane] = mx[k] + base4[k];
    Lsm[wave][k][lane] = s[k];
  }
  __syncthreads();

  if (wave < 4) {
    const int set = wave;
    const int n = blockIdx.x * 256 + set * 64 + lane;
    if (n < N) {
      float gm = Lmx[0][set][lane];
#pragma unroll
      for (int v = 1; v < SPLIT; ++v) gm = fmaxf(gm, Lmx[v][set][lane]);
      float S = 0.f;
#pragma unroll
      for (int v = 0; v < SPLIT; ++v)
        S += Lsm[v][set][lane] * EXP2(Lmx[v][set][lane] - gm);
      out[n] = (gm + __log2f(S)) * LN2;
    }
  }
}

extern "C" void kernel_launch(void* const* d_in, const int* in_sizes, int n_in,
                              void* d_out, int out_size, void* d_ws, size_t ws_size,
                              hipStream_t stream) {
  const float* sample = (const float*)d_in[0];
  const float* mu     = (const float*)d_in[1];
  const float* A      = (const float*)d_in[2];
  const float* w      = (const float*)d_in[3];
  float* out = (float*)d_out;

  const int N = in_sizes[0] / 2;   // sample is (N,2)
  const int M = in_sizes[3];       // w is (M,1)

  float* C = (float*)d_ws;         // 6*M planes + 16-float header + Bpack[M][8] bf16
  const size_t need = ((size_t)6 * M + 16) * 4 + (size_t)M * 16;

  prep_kernel<<<1, 256, 0, stream>>>(mu, A, w, C, M);

  if (ws_size >= need && M % (RMF * 16) == 0 && M % (SPLIT * CH) == 0) {
    gmix_mfma<<<(N + 127) / 128, 512, 0, stream>>>(
        (const float2*)sample, C, out, N, M);
  } else {
    gmix_kernel<<<(N + 255) / 256, 512, 0, stream>>>(sample, C, out, N, M);
  }
}

// Round 8
// 111.769 us; speedup vs baseline: 4.0124x; 1.0259x over previous
//
#include <hip/hip_runtime.h>
#include <math.h>

// GaussianMixture log-likelihood: ll[n] = logsumexp_m( wlog[m] - dx^T G_m dx )
// R13: MFMA path tuned. R12 post-mortem: correct math (absmax 4.0 = R9b), but
// 56us at Occupancy 44% (acc[8] pushed unified regs into the 65-128 band ->
// 14 waves/CU) and ~2.3x VALU-cycle inflation vs source model (accvgpr moves,
// per-batch serial tree->nm->knm->exp chain bunching co-resident waves).
// Fixes, all inside the verified structure:
//  - RMF 8->4 (acc=16 VGPR) + __launch_bounds__(512,8): force <=64 VGPR ->
//    32 waves/CU band. CANARY: VGPR_Count=64, Occupancy ~90%.
//  - v_cvt_u32_f32 (inline asm, 1 inst): HW saturates negatives to 0;
//    bitcast(0)=+0.0 IS the underflow value -> TMIN clamp deleted.
//  - fmaxf(fmaxf(a,b),c) chains -> clang fuses v_max3_f32.
//  - deferred max (T13): knm cached per sample-row; rescale only when
//    __any(cm > mx+40) (wave-uniform). Safety: skipped band => args <= mx+40
//    => u <= K2+40*K1 < 2^31, e <= 2^48, S <= 2048*2^48 << 2^128. First
//    batch always triggers (cm - (-inf) = +inf). Common path has NO
//    dependence on this batch's max -> serial chain broken.
// A/B/D fragment layouts identical to R12 (verified: col=lane&15 comp,
// row=(lane>>4)*4+reg sample). Max coverage stays COMPLETE per batch
// (cm over all 16 accs) before the vote (R5 NaN lesson).
// flag==0 -> exact R7 general path; ws small -> legacy R9b kernel.

#if __has_builtin(__builtin_amdgcn_exp2f)
#define EXP2(x) __builtin_amdgcn_exp2f(x)
#else
#define EXP2(x) exp2f(x)
#endif

typedef float v2f   __attribute__((ext_vector_type(2)));
typedef float f32x4 __attribute__((ext_vector_type(4)));
typedef short bf16x8 __attribute__((ext_vector_type(8)));
typedef float v4f __attribute__((ext_vector_type(4)));
typedef int   i4v __attribute__((ext_vector_type(4)));

#if __has_builtin(__builtin_elementwise_max)
#define VMAX(a, b) __builtin_elementwise_max(a, b)
#else
static __device__ inline v2f VMAX(v2f a, v2f b) {
  v2f r; r.x = fmaxf(a.x, b.x); r.y = fmaxf(a.y, b.y); return r;
}
static __device__ inline v4f VMAX(v4f a, v4f b) {
  v4f r; r.x = fmaxf(a.x, b.x); r.y = fmaxf(a.y, b.y);
  r.z = fmaxf(a.z, b.z); r.w = fmaxf(a.w, b.w); return r;
}
#endif

// Schraudolph exp2 (fp32): y = bitcast(int(x*2^23 + 127*2^23 - C)), C=366393
#define SCH_K1   8388608.0f
#define SCH_K2   1064986823.0f
#define SCH_TMIN 58353856.0f     // legacy path clamp only

#define SPLIT 8
#define CH  16
#define RMF 4                    // MFMAs per epilogue batch (acc = 16 VGPR)
#define THR 40.0f                // deferred-max threshold (safe to ~127)
#define LOG2E 1.44269504088896340736f
#define LN2   0.69314718055994530942f

__device__ __forceinline__ unsigned short f2bf(float f) {
  unsigned u = __builtin_bit_cast(unsigned, f);
  unsigned r = u + 0x7FFFu + ((u >> 16) & 1u);   // RNE
  return (unsigned short)(r >> 16);
}
__device__ __forceinline__ float bf2f(unsigned short h) {
  unsigned u = ((unsigned)h) << 16;
  return __builtin_bit_cast(float, u);
}

// Schraudolph exp2 with HW-saturating u32 cvt: negatives -> 0 -> +0.0f.
// In-range u <= K2 + THR*K1 ~ 1.4e9 < 2^31 -> valid positive float bits.
__device__ __forceinline__ float sch_e(float a, float knm) {
  const float u = fmaf(a, SCH_K1, knm);
  unsigned r;
  asm("v_cvt_u32_f32 %0, %1" : "=v"(r) : "v"(u));
  return __builtin_bit_cast(float, r);
}

// ---------------- prep: coefficients + bf16-packed B fragments ----------------
__global__ __launch_bounds__(256) void prep_kernel(
    const float* __restrict__ mu,
    const float* __restrict__ A,
    const float* __restrict__ w,
    float* __restrict__ C,   // [6][M] planes + header + Bpack[M][8] bf16
    int M) {
  __shared__ float red[256];
  __shared__ int uni[256];
  const int t = threadIdx.x;

  float mx = -INFINITY;
  for (int m = t; m < M; m += 256) mx = fmaxf(mx, w[m]);
  red[t] = mx; __syncthreads();
  for (int s = 128; s > 0; s >>= 1) {
    if (t < s) red[t] = fmaxf(red[t], red[t + s]);
    __syncthreads();
  }
  const float wmax = red[0]; __syncthreads();

  float sum = 0.f;
  for (int m = t; m < M; m += 256) sum += expf(w[m] - wmax);
  red[t] = sum; __syncthreads();
  for (int s = 128; s > 0; s >>= 1) {
    if (t < s) red[t] += red[t + s];
    __syncthreads();
  }
  const float logZ = wmax + logf(red[0]);

  const float r00 = A[0], r01 = A[1], r10 = A[2], r11 = A[3];
  const float rg00 = 0.5f * (r00 * r00 + r01 * r01);
  const float rg01 = 0.5f * (r00 * r10 + r01 * r11);
  const float rg11 = 0.5f * (r10 * r10 + r11 * r11);

  unsigned short* Bp = (unsigned short*)(C + 6 * M + 16);

  int myuni = 1;
  for (int m = t; m < M; m += 256) {
    const float a00 = A[m * 4 + 0], a01 = A[m * 4 + 1];
    const float a10 = A[m * 4 + 2], a11 = A[m * 4 + 3];
    const float g00 = 0.5f * (a00 * a00 + a01 * a01);
    const float g01 = 0.5f * (a00 * a10 + a01 * a11);
    const float g11 = 0.5f * (a10 * a10 + a11 * a11);
    const float g01s = 2.0f * g01;
    const float det = g00 * g11 - g01 * g01;
    const float wlog = (w[m] - logZ) + 0.5f * logf(det);
    const float mu0 = mu[m * 2 + 0], mu1 = mu[m * 2 + 1];
    const float c0 = wlog - (g00 * mu0 * mu0 + g01s * mu0 * mu1 + g11 * mu1 * mu1);
    const float c2 = 2.0f * g00 * mu0 + g01s * mu1;
    const float c4 = 2.0f * g11 * mu1 + g01s * mu0;
    const float C0v = LOG2E * c0;
    const float C2v = LOG2E * c2;
    const float C4v = LOG2E * c4;
    C[0 * M + m] = C0v;
    C[1 * M + m] = LOG2E * -g00;
    C[2 * M + m] = C2v;
    C[3 * M + m] = LOG2E * -g11;
    C[4 * M + m] = C4v;
    C[5 * M + m] = LOG2E * -g01s;
    const unsigned short c2h = f2bf(C2v);
    const unsigned short c2l = f2bf(C2v - bf2f(c2h));
    const unsigned short c4h = f2bf(C4v);
    const unsigned short c4l = f2bf(C4v - bf2f(c4h));
    const unsigned short c0h = f2bf(C0v);
    const unsigned short c0l = f2bf(C0v - bf2f(c0h));
    Bp[m * 8 + 0] = c2h; Bp[m * 8 + 1] = c2h; Bp[m * 8 + 2] = c2l;
    Bp[m * 8 + 3] = c4h; Bp[m * 8 + 4] = c4h; Bp[m * 8 + 5] = c4l;
    Bp[m * 8 + 6] = c0h; Bp[m * 8 + 7] = c0l;
    myuni &= (g00 == rg00) & (g01 == rg01) & (g11 == rg11);
  }
  uni[t] = myuni; __syncthreads();
  for (int s = 128; s > 0; s >>= 1) {
    if (t < s) uni[t] &= uni[t + s];
    __syncthreads();
  }
  if (t == 0) {
    ((int*)C)[6 * M + 0] = uni[0];
    C[6 * M + 1] = LOG2E * -rg00;        // cb1
    C[6 * M + 2] = LOG2E * -rg11;        // cb3
    C[6 * M + 3] = LOG2E * -2.0f * rg01; // cb5
  }
}

#define MERGE(MXJ, SJ, OFF) do {                                             \
    const float om = __shfl_xor(MXJ, OFF, 64);                               \
    const float os = __shfl_xor(SJ, OFF, 64);                                \
    const float nm = fmaxf(MXJ, om);                                         \
    SJ = SJ * EXP2(MXJ - nm) + os * EXP2(om - nm);                           \
    MXJ = nm;                                                                \
  } while (0)

// grid: (N+127)/128 blocks x 512 threads; wave w owns samples blk*128+w*16+[0,16)
__global__ __launch_bounds__(512, 8) void gmix_mfma(
    const float2* __restrict__ xs,
    const float* __restrict__ C,
    float* __restrict__ out,
    int N, int M) {
  __shared__ float Lmx[SPLIT][2][64];
  __shared__ float Lsm[SPLIT][2][64];
  const int lane = threadIdx.x & 63;
  const int wave = __builtin_amdgcn_readfirstlane((int)(threadIdx.x >> 6));
  const int flag = ((const int*)C)[6 * M + 0];
  const float cb1 = C[6 * M + 1];
  const float cb3 = C[6 * M + 2];
  const float cb5 = C[6 * M + 3];

  if (flag) {
    const int sbase = blockIdx.x * 128 + wave * 16;
    const int col = lane & 15;
    const bf16x8* __restrict__ Bcol = (const bf16x8*)(C + 6 * M + 16) + col;

    const int sA = sbase + col;
    const float2 xa = (sA < N) ? xs[sA] : make_float2(0.f, 0.f);
    bf16x8 afrag = (bf16x8){0, 0, 0, 0, 0, 0, 0, 0};
    if (lane < 16) {
      const unsigned short x0h = f2bf(xa.x);
      const unsigned short x0l = f2bf(xa.x - bf2f(x0h));
      const unsigned short x1h = f2bf(xa.y);
      const unsigned short x1l = f2bf(xa.y - bf2f(x1h));
      afrag = (bf16x8){(short)x0h, (short)x0l, (short)x0h,
                       (short)x1h, (short)x1l, (short)x1h,
                       (short)0x3F80, (short)0x3F80};   // 1.0bf16 (c0h,c0l)
    }

    float mx0 = -INFINITY, mx1 = -INFINITY, mx2 = -INFINITY, mx3 = -INFINITY;
    float s0 = 0.f, s1 = 0.f, s2 = 0.f, s3 = 0.f;
    float knm0 = 0.f, knm1 = 0.f, knm2 = 0.f, knm3 = 0.f;
    const f32x4 z4 = {0.f, 0.f, 0.f, 0.f};
    const int rounds = M / (RMF * 16);

    for (int t = 0; t < rounds; ++t) {
      f32x4 acc[RMF];
#pragma unroll
      for (int r = 0; r < RMF; ++r) {
        const bf16x8 bfrag = Bcol[t * (RMF * 16) + r * 16];
        acc[r] = __builtin_amdgcn_mfma_f32_16x16x32_bf16(afrag, bfrag, z4, 0, 0, 0);
      }
      // COMPLETE per-batch max (v_max3-friendly chains), then uniform vote
      const float cm0 = fmaxf(fmaxf(fmaxf(acc[0][0], acc[1][0]), acc[2][0]), acc[3][0]);
      const float cm1 = fmaxf(fmaxf(fmaxf(acc[0][1], acc[1][1]), acc[2][1]), acc[3][1]);
      const float cm2 = fmaxf(fmaxf(fmaxf(acc[0][2], acc[1][2]), acc[2][2]), acc[3][2]);
      const float cm3 = fmaxf(fmaxf(fmaxf(acc[0][3], acc[1][3]), acc[2][3]), acc[3][3]);
      const float d = fmaxf(fmaxf(cm0 - mx0, cm1 - mx1),
                            fmaxf(cm2 - mx2, cm3 - mx3));
      if (__any(d > THR)) {   // rare after warm-up; first batch always fires
#define RESC(J) do {                                                         \
          const float nm_ = fmaxf(mx##J, cm##J);                             \
          s##J *= EXP2(mx##J - nm_);                                         \
          mx##J = nm_;                                                       \
          knm##J = fmaf(nm_, -SCH_K1, SCH_K2);                               \
        } while (0)
        RESC(0); RESC(1); RESC(2); RESC(3);
#undef RESC
      }
      // common path: no dependence on this batch's max
#define EPIC(J) do {                                                         \
        const float e0 = sch_e(acc[0][J], knm##J);                           \
        const float e1 = sch_e(acc[1][J], knm##J);                           \
        const float e2 = sch_e(acc[2][J], knm##J);                           \
        const float e3 = sch_e(acc[3][J], knm##J);                           \
        s##J += (e0 + e1) + (e2 + e3);                                       \
      } while (0)
      EPIC(0); EPIC(1); EPIC(2); EPIC(3);
#undef EPIC
    }

    // merge across the 16 comp-lanes of each row group
#pragma unroll
    for (int off = 1; off < 16; off <<= 1) {
      MERGE(mx0, s0, off);
      MERGE(mx1, s1, off);
      MERGE(mx2, s2, off);
      MERGE(mx3, s3, off);
    }

    if (col == 0) {
      const int g = lane >> 4;
#define OUTJ(J, MXJ, SJ) do {                                                \
        const int sr = sbase + g * 4 + (J);                                  \
        if (sr < N) {                                                        \
          const float2 xo = xs[sr];                                          \
          const float base = cb1 * xo.x * xo.x + cb3 * xo.y * xo.y +         \
                             cb5 * xo.x * xo.y;                              \
          out[sr] = (MXJ + base + __log2f(SJ)) * LN2;                        \
        }                                                                    \
      } while (0)
      OUTJ(0, mx0, s0);
      OUTJ(1, mx1, s1);
      OUTJ(2, mx2, s2);
      OUTJ(3, mx3, s3);
#undef OUTJ
    }
  } else {
    // exact general path (R7): 128 samples/block, 8-wave M-split, v2f, hw exp2
    const int nA = blockIdx.x * 128 + lane;
    const int nB = nA + 64;
    const float2 xA = (nA < N) ? xs[nA] : make_float2(0.f, 0.f);
    const float2 xB = (nB < N) ? xs[nB] : make_float2(0.f, 0.f);
    const v2f x0p = {xA.x, xB.x};
    const v2f x1p = {xA.y, xB.y};

    const int Mq = M / SPLIT;
    const int m0 = wave * Mq;
    const float* __restrict__ C0 = C + m0;
    const float* __restrict__ C1 = C + M + m0;
    const float* __restrict__ C2 = C + 2 * M + m0;
    const float* __restrict__ C3 = C + 3 * M + m0;
    const float* __restrict__ C4 = C + 4 * M + m0;
    const float* __restrict__ C5 = C + 5 * M + m0;

    v2f mx = {-INFINITY, -INFINITY};
    v2f sacc = {0.f, 0.f};
    for (int m = 0; m < Mq; m += CH) {
      v2f a[CH];
#pragma unroll
      for (int j = 0; j < CH; ++j) {
        const float c0 = C0[m + j], c1 = C1[m + j], c2 = C2[m + j];
        const float c3 = C3[m + j], c4 = C4[m + j], c5 = C5[m + j];
        v2f u = x0p * c1 + c2;
        u = x1p * c5 + u;
        v2f v = x1p * c3 + c4;
        v2f r = u * x0p + c0;
        a[j] = v * x1p + r;
      }
      v2f t0 = VMAX(a[0], a[1]);
      v2f t1 = VMAX(a[2], a[3]);
      v2f t2 = VMAX(a[4], a[5]);
      v2f t3 = VMAX(a[6], a[7]);
#pragma unroll
      for (int j = 8; j < CH; j += 4) {
        t0 = VMAX(t0, a[j]);     t1 = VMAX(t1, a[j + 1]);
        t2 = VMAX(t2, a[j + 2]); t3 = VMAX(t3, a[j + 3]);
      }
      const v2f cm = VMAX(VMAX(t0, t1), VMAX(t2, t3));
      const v2f nm = VMAX(mx, cm);
      v2f resc; resc.x = EXP2(mx.x - nm.x); resc.y = EXP2(mx.y - nm.y);
      v2f l0 = {0.f, 0.f}, l1 = {0.f, 0.f};
#pragma unroll
      for (int j = 0; j < CH; j += 2) {
        const v2f d0 = a[j] - nm, d1 = a[j + 1] - nm;
        v2f e0, e1;
        e0.x = EXP2(d0.x); e0.y = EXP2(d0.y);
        e1.x = EXP2(d1.x); e1.y = EXP2(d1.y);
        l0 += e0; l1 += e1;
      }
      sacc = sacc * resc + (l0 + l1);
      mx = nm;
    }
    const v2f base = cb1 * x0p * x0p + cb3 * x1p * x1p + cb5 * x0p * x1p;
#pragma unroll
    for (int k = 0; k < 2; ++k) {
      Lmx[wave][k][lane] = mx[k] + base[k];
      Lsm[wave][k][lane] = sacc[k];
    }
    __syncthreads();
    if (wave < 2) {
      const int n = blockIdx.x * 128 + wave * 64 + lane;
      if (n < N) {
        float gm = Lmx[0][wave][lane];
#pragma unroll
        for (int v = 1; v < SPLIT; ++v) gm = fmaxf(gm, Lmx[v][wave][lane]);
        float S = 0.f;
#pragma unroll
        for (int v = 0; v < SPLIT; ++v)
          S += Lsm[v][wave][lane] * EXP2(Lmx[v][wave][lane] - gm);
        out[n] = (gm + __log2f(S)) * LN2;
      }
    }
  }
}

// ---------------- legacy exact fallback (R9b structure) ----------------
__global__ __launch_bounds__(512, 4) void gmix_kernel(
    const float* __restrict__ sample,
    const float* __restrict__ C,
    float* __restrict__ out,
    int N, int M) {
  __shared__ float Lmx[SPLIT][4][64];
  __shared__ float Lsm[SPLIT][4][64];

  const int lane = threadIdx.x & 63;
  const int wave = __builtin_amdgcn_readfirstlane((int)(threadIdx.x >> 6));
  const int n0 = blockIdx.x * 256 + lane;

  float2 xs0 = (n0       < N) ? ((const float2*)sample)[n0      ] : make_float2(0.f, 0.f);
  float2 xs1 = (n0 + 64  < N) ? ((const float2*)sample)[n0 + 64 ] : make_float2(0.f, 0.f);
  float2 xs2 = (n0 + 128 < N) ? ((const float2*)sample)[n0 + 128] : make_float2(0.f, 0.f);
  float2 xs3 = (n0 + 192 < N) ? ((const float2*)sample)[n0 + 192] : make_float2(0.f, 0.f);
  const v4f x0q = {xs0.x, xs1.x, xs2.x, xs3.x};
  const v4f x1q = {xs0.y, xs1.y, xs2.y, xs3.y};

  const int flag = ((const int*)C)[6 * M + 0];
  const float cb1 = C[6 * M + 1];
  const float cb3 = C[6 * M + 2];
  const float cb5 = C[6 * M + 3];

  const int Mq = M / SPLIT;
  const int m0 = wave * Mq;
  const float* __restrict__ C0 = C + m0;
  const float* __restrict__ C1 = C + M + m0;
  const float* __restrict__ C2 = C + 2 * M + m0;
  const float* __restrict__ C3 = C + 3 * M + m0;
  const float* __restrict__ C4 = C + 4 * M + m0;
  const float* __restrict__ C5 = C + 5 * M + m0;

  v4f base4 = {0.f, 0.f, 0.f, 0.f};
  v4f mx = {-INFINITY, -INFINITY, -INFINITY, -INFINITY};
  v4f s  = {0.f, 0.f, 0.f, 0.f};
  const v4f tminv4 = {SCH_TMIN, SCH_TMIN, SCH_TMIN, SCH_TMIN};

  if (flag) {
    base4 = cb1 * x0q * x0q + cb3 * x1q * x1q + cb5 * x0q * x1q;
    for (int m = 0; m < Mq; m += CH) {
      v4f a[CH];
#pragma unroll
      for (int j = 0; j < CH; ++j) {
        const float c0 = C0[m + j], c2 = C2[m + j], c4 = C4[m + j];
        v4f t = x0q * c2 + c0;
        a[j] = x1q * c4 + t;
      }
      v4f t0 = VMAX(a[0], a[1]);
      v4f t1 = VMAX(a[2], a[3]);
      v4f t2 = VMAX(a[4], a[5]);
      v4f t3 = VMAX(a[6], a[7]);
#pragma unroll
      for (int j = 8; j < CH; j += 4) {
        t0 = VMAX(t0, a[j]);     t1 = VMAX(t1, a[j + 1]);
        t2 = VMAX(t2, a[j + 2]); t3 = VMAX(t3, a[j + 3]);
      }
      const v4f cm = VMAX(VMAX(t0, t1), VMAX(t2, t3));
      const v4f nm = VMAX(mx, cm);
      v4f resc;
      resc.x = EXP2(mx.x - nm.x); resc.y = EXP2(mx.y - nm.y);
      resc.z = EXP2(mx.z - nm.z); resc.w = EXP2(mx.w - nm.w);
      const v4f knm = SCH_K2 - nm * SCH_K1;
      v4f l0 = {0.f, 0.f, 0.f, 0.f}, l1 = {0.f, 0.f, 0.f, 0.f};
#pragma unroll
      for (int j = 0; j < CH; j += 2) {
        v4f u0 = a[j]     * SCH_K1 + knm;
        v4f u1 = a[j + 1] * SCH_K1 + knm;
        u0 = VMAX(u0, tminv4);
        u1 = VMAX(u1, tminv4);
        const i4v iv0 = __builtin_convertvector(u0, i4v);
        const i4v iv1 = __builtin_convertvector(u1, i4v);
        l0 += __builtin_bit_cast(v4f, iv0);
        l1 += __builtin_bit_cast(v4f, iv1);
      }
      s = s * resc + (l0 + l1);
      mx = nm;
    }
  } else {
    for (int m = 0; m < Mq; m += CH) {
      v4f a[CH];
#pragma unroll
      for (int j = 0; j < CH; ++j) {
        const float c0 = C0[m + j], c1 = C1[m + j], c2 = C2[m + j];
        const float c3 = C3[m + j], c4 = C4[m + j], c5 = C5[m + j];
        v4f u = x0q * c1 + c2;
        u = x1q * c5 + u;
        v4f v = x1q * c3 + c4;
        v4f r = u * x0q + c0;
        a[j] = v * x1q + r;
      }
      v4f t0 = VMAX(a[0], a[1]);
      v4f t1 = VMAX(a[2], a[3]);
      v4f t2 = VMAX(a[4], a[5]);
      v4f t3 = VMAX(a[6], a[7]);
#pragma unroll
      for (int j = 8; j < CH; j += 4) {
        t0 = VMAX(t0, a[j]);     t1 = VMAX(t1, a[j + 1]);
        t2 = VMAX(t2, a[j + 2]); t3 = VMAX(t3, a[j + 3]);
      }
      const v4f cm = VMAX(VMAX(t0, t1), VMAX(t2, t3));
      const v4f nm = VMAX(mx, cm);
      v4f resc;
      resc.x = EXP2(mx.x - nm.x); resc.y = EXP2(mx.y - nm.y);
      resc.z = EXP2(mx.z - nm.z); resc.w = EXP2(mx.w - nm.w);
      v4f l0 = {0.f, 0.f, 0.f, 0.f}, l1 = {0.f, 0.f, 0.f, 0.f};
#pragma unroll
      for (int j = 0; j < CH; j += 2) {
        v4f d0 = a[j] - nm, d1 = a[j + 1] - nm;
        v4f e0, e1;
        e0.x = EXP2(d0.x); e0.y = EXP2(d0.y); e0.z = EXP2(d0.z); e0.w = EXP2(d0.w);
        e1.x = EXP2(d1.x); e1.y = EXP2(d1.y); e1.z = EXP2(d1.z); e1.w = EXP2(d1.w);
        l0 += e0; l1 += e1;
      }
      s = s * resc + (l0 + l1);
      mx = nm;
    }
  }

#pragma unroll
  for (int k = 0; k < 4; ++k) {
    Lmx[wave][k][lane] = mx[k] + base4[k];
    Lsm[wave][k][lane] = s[k];
  }
  __syncthreads();

  if (wave < 4) {
    const int set = wave;
    const int n = blockIdx.x * 256 + set * 64 + lane;
    if (n < N) {
      float gm = Lmx[0][set][lane];
#pragma unroll
      for (int v = 1; v < SPLIT; ++v) gm = fmaxf(gm, Lmx[v][set][lane]);
      float S = 0.f;
#pragma unroll
      for (int v = 0; v < SPLIT; ++v)
        S += Lsm[v][set][lane] * EXP2(Lmx[v][set][lane] - gm);
      out[n] = (gm + __log2f(S)) * LN2;
    }
  }
}

extern "C" void kernel_launch(void* const* d_in, const int* in_sizes, int n_in,
                              void* d_out, int out_size, void* d_ws, size_t ws_size,
                              hipStream_t stream) {
  const float* sample = (const float*)d_in[0];
  const float* mu     = (const float*)d_in[1];
  const float* A      = (const float*)d_in[2];
  const float* w      = (const float*)d_in[3];
  float* out = (float*)d_out;

  const int N = in_sizes[0] / 2;   // sample is (N,2)
  const int M = in_sizes[3];       // w is (M,1)

  float* C = (float*)d_ws;         // 6*M planes + 16-float header + Bpack[M][8] bf16
  const size_t need = ((size_t)6 * M + 16) * 4 + (size_t)M * 16;

  prep_kernel<<<1, 256, 0, stream>>>(mu, A, w, C, M);

  if (ws_size >= need && M % (RMF * 16) == 0 && M % (SPLIT * CH) == 0) {
    gmix_mfma<<<(N + 127) / 128, 512, 0, stream>>>(
        (const float2*)sample, C, out, N, M);
  } else {
    gmix_kernel<<<(N + 255) / 256, 512, 0, stream>>>(sample, C, out, N, M);
  }
}

// Round 9
// 111.749 us; speedup vs baseline: 4.0132x; 1.0002x over previous
//
#include <hip/hip_runtime.h>
#include <math.h>

// GaussianMixture log-likelihood: ll[n] = logsumexp_m( wlog[m] - dx^T G_m dx )
// R14: R13 MFMA structure + (1) PACKED epilogue: MFMA acc f32x4 gives free
// VGPR-adjacent (row0,row1)/(row2,row3) pairs -> v_pk_fma/pk_max/pk_add for
// scale+cm+accumulate; only the cvt stays scalar. ~52 inst/round vs R13's 75.
// (2) prep parallelized: logZ is a UNIFORM shift -> folded at the OUTPUT
// stage instead of into C0; prep block 0 does logZ+uni+header, blocks 1..N
// write planes+Bpack grid-strided (was 1 block / 1 CU serial).
// Deferred max (THR=40, wave-uniform vote) + HW-saturating v_cvt_u32_f32
// (negatives->0 == exact underflow) kept from R13 (absmax 8.0 passed).
// A/B/D fragment layouts unchanged (verified R12/R13: col=lane&15 comp,
// row=(lane>>4)*4+reg sample). Per-batch max coverage stays COMPLETE before
// the vote (R5 NaN lesson). flag==0 -> exact general path; small ws -> legacy.

#if __has_builtin(__builtin_amdgcn_exp2f)
#define EXP2(x) __builtin_amdgcn_exp2f(x)
#else
#define EXP2(x) exp2f(x)
#endif

typedef float v2f   __attribute__((ext_vector_type(2)));
typedef float f32x4 __attribute__((ext_vector_type(4)));
typedef short bf16x8 __attribute__((ext_vector_type(8)));
typedef float v4f __attribute__((ext_vector_type(4)));
typedef int   i4v __attribute__((ext_vector_type(4)));

#if __has_builtin(__builtin_elementwise_max)
#define VMAX(a, b) __builtin_elementwise_max(a, b)
#else
static __device__ inline v2f VMAX(v2f a, v2f b) {
  v2f r; r.x = fmaxf(a.x, b.x); r.y = fmaxf(a.y, b.y); return r;
}
static __device__ inline v4f VMAX(v4f a, v4f b) {
  v4f r; r.x = fmaxf(a.x, b.x); r.y = fmaxf(a.y, b.y);
  r.z = fmaxf(a.z, b.z); r.w = fmaxf(a.w, b.w); return r;
}
#endif

#define LO2(v) __builtin_shufflevector((v), (v), 0, 1)   // f32x4 -> v2f rows 0,1
#define HI2(v) __builtin_shufflevector((v), (v), 2, 3)   // f32x4 -> v2f rows 2,3

// Schraudolph exp2 (fp32): y = bitcast(int(x*2^23 + 127*2^23 - C)), C=366393
#define SCH_K1   8388608.0f
#define SCH_K2   1064986823.0f
#define SCH_TMIN 58353856.0f     // legacy path clamp only

#define SPLIT 8
#define CH  16
#define RMF 4                    // MFMAs per epilogue batch (acc = 16 VGPR)
#define THR 40.0f                // deferred-max threshold (safe to ~127)
#define LOG2E 1.44269504088896340736f
#define LN2   0.69314718055994530942f

__device__ __forceinline__ unsigned short f2bf(float f) {
  unsigned u = __builtin_bit_cast(unsigned, f);
  unsigned r = u + 0x7FFFu + ((u >> 16) & 1u);   // RNE
  return (unsigned short)(r >> 16);
}
__device__ __forceinline__ float bf2f(unsigned short h) {
  unsigned u = ((unsigned)h) << 16;
  return __builtin_bit_cast(float, u);
}

// HW-saturating u32 cvt: negatives -> 0 -> bitcast +0.0f (= exact underflow).
__device__ __forceinline__ float sch_cvt(float u) {
  unsigned r;
  asm("v_cvt_u32_f32 %0, %1" : "=v"(r) : "v"(u));
  return __builtin_bit_cast(float, r);
}

// ---------------- prep: block 0 = reductions/header; others = planes+Bpack.
// C0 plane NO LONGER includes -logZ (folded at output via header slot 4). ----
__global__ __launch_bounds__(256) void prep_kernel(
    const float* __restrict__ mu,
    const float* __restrict__ A,
    const float* __restrict__ w,
    float* __restrict__ C,   // [6][M] planes + 16-float header + Bpack[M][8]
    int M) {
  const int t = threadIdx.x;

  if (blockIdx.x == 0) {
    __shared__ float red[256];
    __shared__ int uni[256];

    float mx = -INFINITY;
    for (int m = t; m < M; m += 256) mx = fmaxf(mx, w[m]);
    red[t] = mx; __syncthreads();
    for (int s = 128; s > 0; s >>= 1) {
      if (t < s) red[t] = fmaxf(red[t], red[t + s]);
      __syncthreads();
    }
    const float wmax = red[0]; __syncthreads();

    float sum = 0.f;
    for (int m = t; m < M; m += 256) sum += expf(w[m] - wmax);
    red[t] = sum; __syncthreads();
    for (int s = 128; s > 0; s >>= 1) {
      if (t < s) red[t] += red[t + s];
      __syncthreads();
    }
    const float logZ = wmax + logf(red[0]);

    const float r00 = A[0], r01 = A[1], r10 = A[2], r11 = A[3];
    const float rg00 = 0.5f * (r00 * r00 + r01 * r01);
    const float rg01 = 0.5f * (r00 * r10 + r01 * r11);
    const float rg11 = 0.5f * (r10 * r10 + r11 * r11);

    int myuni = 1;
    for (int m = t; m < M; m += 256) {
      const float a00 = A[m * 4 + 0], a01 = A[m * 4 + 1];
      const float a10 = A[m * 4 + 2], a11 = A[m * 4 + 3];
      const float g00 = 0.5f * (a00 * a00 + a01 * a01);
      const float g01 = 0.5f * (a00 * a10 + a01 * a11);
      const float g11 = 0.5f * (a10 * a10 + a11 * a11);
      myuni &= (g00 == rg00) & (g01 == rg01) & (g11 == rg11);
    }
    uni[t] = myuni; __syncthreads();
    for (int s = 128; s > 0; s >>= 1) {
      if (t < s) uni[t] &= uni[t + s];
      __syncthreads();
    }
    if (t == 0) {
      ((int*)C)[6 * M + 0] = uni[0];
      C[6 * M + 1] = LOG2E * -rg00;        // cb1
      C[6 * M + 2] = LOG2E * -rg11;        // cb3
      C[6 * M + 3] = LOG2E * -2.0f * rg01; // cb5
      C[6 * M + 4] = LOG2E * logZ;         // logZ in log2 units
    }
    return;
  }

  // plane/Bpack writers (no logZ dependency)
  unsigned short* Bp = (unsigned short*)(C + 6 * M + 16);
  const int nwb = (int)gridDim.x - 1;
  for (int m = ((int)blockIdx.x - 1) * 256 + t; m < M; m += nwb * 256) {
    const float a00 = A[m * 4 + 0], a01 = A[m * 4 + 1];
    const float a10 = A[m * 4 + 2], a11 = A[m * 4 + 3];
    const float g00 = 0.5f * (a00 * a00 + a01 * a01);
    const float g01 = 0.5f * (a00 * a10 + a01 * a11);
    const float g11 = 0.5f * (a10 * a10 + a11 * a11);
    const float g01s = 2.0f * g01;
    const float det = g00 * g11 - g01 * g01;
    const float wlog = w[m] + 0.5f * logf(det);   // logZ folded at output
    const float mu0 = mu[m * 2 + 0], mu1 = mu[m * 2 + 1];
    const float c0 = wlog - (g00 * mu0 * mu0 + g01s * mu0 * mu1 + g11 * mu1 * mu1);
    const float c2 = 2.0f * g00 * mu0 + g01s * mu1;
    const float c4 = 2.0f * g11 * mu1 + g01s * mu0;
    const float C0v = LOG2E * c0;
    const float C2v = LOG2E * c2;
    const float C4v = LOG2E * c4;
    C[0 * M + m] = C0v;
    C[1 * M + m] = LOG2E * -g00;
    C[2 * M + m] = C2v;
    C[3 * M + m] = LOG2E * -g11;
    C[4 * M + m] = C4v;
    C[5 * M + m] = LOG2E * -g01s;
    const unsigned short c2h = f2bf(C2v);
    const unsigned short c2l = f2bf(C2v - bf2f(c2h));
    const unsigned short c4h = f2bf(C4v);
    const unsigned short c4l = f2bf(C4v - bf2f(c4h));
    const unsigned short c0h = f2bf(C0v);
    const unsigned short c0l = f2bf(C0v - bf2f(c0h));
    Bp[m * 8 + 0] = c2h; Bp[m * 8 + 1] = c2h; Bp[m * 8 + 2] = c2l;
    Bp[m * 8 + 3] = c4h; Bp[m * 8 + 4] = c4h; Bp[m * 8 + 5] = c4l;
    Bp[m * 8 + 6] = c0h; Bp[m * 8 + 7] = c0l;
  }
}

#define MERGE(MXJ, SJ, OFF) do {                                             \
    const float om = __shfl_xor(MXJ, OFF, 64);                               \
    const float os = __shfl_xor(SJ, OFF, 64);                                \
    const float nm = fmaxf(MXJ, om);                                         \
    SJ = SJ * EXP2(MXJ - nm) + os * EXP2(om - nm);                           \
    MXJ = nm;                                                                \
  } while (0)

// grid: (N+127)/128 blocks x 512 threads; wave w owns samples blk*128+w*16+[0,16)
__global__ __launch_bounds__(512, 8) void gmix_mfma(
    const float2* __restrict__ xs,
    const float* __restrict__ C,
    float* __restrict__ out,
    int N, int M) {
  __shared__ float Lmx[SPLIT][2][64];
  __shared__ float Lsm[SPLIT][2][64];
  const int lane = threadIdx.x & 63;
  const int wave = __builtin_amdgcn_readfirstlane((int)(threadIdx.x >> 6));
  const int flag = ((const int*)C)[6 * M + 0];
  const float cb1 = C[6 * M + 1];
  const float cb3 = C[6 * M + 2];
  const float cb5 = C[6 * M + 3];
  const float logZh = C[6 * M + 4];

  if (flag) {
    const int sbase = blockIdx.x * 128 + wave * 16;
    const int col = lane & 15;
    const bf16x8* __restrict__ Bcol = (const bf16x8*)(C + 6 * M + 16) + col;

    const int sA = sbase + col;
    const float2 xa = (sA < N) ? xs[sA] : make_float2(0.f, 0.f);
    bf16x8 afrag = (bf16x8){0, 0, 0, 0, 0, 0, 0, 0};
    if (lane < 16) {
      const unsigned short x0h = f2bf(xa.x);
      const unsigned short x0l = f2bf(xa.x - bf2f(x0h));
      const unsigned short x1h = f2bf(xa.y);
      const unsigned short x1l = f2bf(xa.y - bf2f(x1h));
      afrag = (bf16x8){(short)x0h, (short)x0l, (short)x0h,
                       (short)x1h, (short)x1l, (short)x1h,
                       (short)0x3F80, (short)0x3F80};   // 1.0bf16 (c0h,c0l)
    }

    // packed per-row-pair state: .x = row0/2, .y = row1/3
    v2f mx01 = {-INFINITY, -INFINITY}, mx23 = {-INFINITY, -INFINITY};
    v2f s01 = {0.f, 0.f}, s23 = {0.f, 0.f};
    v2f knm01 = {0.f, 0.f}, knm23 = {0.f, 0.f};
    const f32x4 z4 = {0.f, 0.f, 0.f, 0.f};
    const int rounds = M / (RMF * 16);

    for (int t = 0; t < rounds; ++t) {
      f32x4 acc[RMF];
#pragma unroll
      for (int r = 0; r < RMF; ++r) {
        const bf16x8 bfrag = Bcol[t * (RMF * 16) + r * 16];
        acc[r] = __builtin_amdgcn_mfma_f32_16x16x32_bf16(afrag, bfrag, z4, 0, 0, 0);
      }
      // COMPLETE per-batch max as packed pairs (rows 0,1 | rows 2,3)
      const v2f cm01 = VMAX(VMAX(LO2(acc[0]), LO2(acc[1])),
                            VMAX(LO2(acc[2]), LO2(acc[3])));
      const v2f cm23 = VMAX(VMAX(HI2(acc[0]), HI2(acc[1])),
                            VMAX(HI2(acc[2]), HI2(acc[3])));
      const v2f dp = VMAX(cm01 - mx01, cm23 - mx23);
      const float dmax = fmaxf(dp.x, dp.y);
      if (__any(dmax > THR)) {   // rare after warm-up; round 0 always fires
        const v2f nm01 = VMAX(mx01, cm01);
        const v2f nm23 = VMAX(mx23, cm23);
        v2f r01, r23;
        r01.x = EXP2(mx01.x - nm01.x); r01.y = EXP2(mx01.y - nm01.y);
        r23.x = EXP2(mx23.x - nm23.x); r23.y = EXP2(mx23.y - nm23.y);
        s01 *= r01; s23 *= r23;
        mx01 = nm01; mx23 = nm23;
        knm01 = SCH_K2 - nm01 * SCH_K1;   // v_pk_fma
        knm23 = SCH_K2 - nm23 * SCH_K1;
      }
      // common path: packed scale + scalar sat-cvt + packed accumulate
#pragma unroll
      for (int r = 0; r < RMF; ++r) {
        const v2f u01 = LO2(acc[r]) * SCH_K1 + knm01;   // v_pk_fma_f32
        const v2f u23 = HI2(acc[r]) * SCH_K1 + knm23;
        v2f e01, e23;
        e01.x = sch_cvt(u01.x); e01.y = sch_cvt(u01.y);
        e23.x = sch_cvt(u23.x); e23.y = sch_cvt(u23.y);
        s01 += e01;                                      // v_pk_add_f32
        s23 += e23;
      }
    }

    float mx0 = mx01.x, mx1 = mx01.y, mx2 = mx23.x, mx3 = mx23.y;
    float s0 = s01.x, s1 = s01.y, s2 = s23.x, s3 = s23.y;

    // merge across the 16 comp-lanes of each row group
#pragma unroll
    for (int off = 1; off < 16; off <<= 1) {
      MERGE(mx0, s0, off);
      MERGE(mx1, s1, off);
      MERGE(mx2, s2, off);
      MERGE(mx3, s3, off);
    }

    if (col == 0) {
      const int g = lane >> 4;
#define OUTJ(J, MXJ, SJ) do {                                                \
        const int sr = sbase + g * 4 + (J);                                  \
        if (sr < N) {                                                        \
          const float2 xo = xs[sr];                                          \
          const float base = cb1 * xo.x * xo.x + cb3 * xo.y * xo.y +         \
                             cb5 * xo.x * xo.y - logZh;                      \
          out[sr] = (MXJ + base + __log2f(SJ)) * LN2;                        \
        }                                                                    \
      } while (0)
      OUTJ(0, mx0, s0);
      OUTJ(1, mx1, s1);
      OUTJ(2, mx2, s2);
      OUTJ(3, mx3, s3);
#undef OUTJ
    }
  } else {
    // exact general path (R7): 128 samples/block, 8-wave M-split, v2f, hw exp2
    const int nA = blockIdx.x * 128 + lane;
    const int nB = nA + 64;
    const float2 xA = (nA < N) ? xs[nA] : make_float2(0.f, 0.f);
    const float2 xB = (nB < N) ? xs[nB] : make_float2(0.f, 0.f);
    const v2f x0p = {xA.x, xB.x};
    const v2f x1p = {xA.y, xB.y};

    const int Mq = M / SPLIT;
    const int m0 = wave * Mq;
    const float* __restrict__ C0 = C + m0;
    const float* __restrict__ C1 = C + M + m0;
    const float* __restrict__ C2 = C + 2 * M + m0;
    const float* __restrict__ C3 = C + 3 * M + m0;
    const float* __restrict__ C4 = C + 4 * M + m0;
    const float* __restrict__ C5 = C + 5 * M + m0;

    v2f mx = {-INFINITY, -INFINITY};
    v2f sacc = {0.f, 0.f};
    for (int m = 0; m < Mq; m += CH) {
      v2f a[CH];
#pragma unroll
      for (int j = 0; j < CH; ++j) {
        const float c0 = C0[m + j], c1 = C1[m + j], c2 = C2[m + j];
        const float c3 = C3[m + j], c4 = C4[m + j], c5 = C5[m + j];
        v2f u = x0p * c1 + c2;
        u = x1p * c5 + u;
        v2f v = x1p * c3 + c4;
        v2f r = u * x0p + c0;
        a[j] = v * x1p + r;
      }
      v2f t0 = VMAX(a[0], a[1]);
      v2f t1 = VMAX(a[2], a[3]);
      v2f t2 = VMAX(a[4], a[5]);
      v2f t3 = VMAX(a[6], a[7]);
#pragma unroll
      for (int j = 8; j < CH; j += 4) {
        t0 = VMAX(t0, a[j]);     t1 = VMAX(t1, a[j + 1]);
        t2 = VMAX(t2, a[j + 2]); t3 = VMAX(t3, a[j + 3]);
      }
      const v2f cm = VMAX(VMAX(t0, t1), VMAX(t2, t3));
      const v2f nm = VMAX(mx, cm);
      v2f resc; resc.x = EXP2(mx.x - nm.x); resc.y = EXP2(mx.y - nm.y);
      v2f l0 = {0.f, 0.f}, l1 = {0.f, 0.f};
#pragma unroll
      for (int j = 0; j < CH; j += 2) {
        const v2f d0 = a[j] - nm, d1 = a[j + 1] - nm;
        v2f e0, e1;
        e0.x = EXP2(d0.x); e0.y = EXP2(d0.y);
        e1.x = EXP2(d1.x); e1.y = EXP2(d1.y);
        l0 += e0; l1 += e1;
      }
      sacc = sacc * resc + (l0 + l1);
      mx = nm;
    }
    const v2f base = cb1 * x0p * x0p + cb3 * x1p * x1p + cb5 * x0p * x1p
                     - (v2f){logZh, logZh};
#pragma unroll
    for (int k = 0; k < 2; ++k) {
      Lmx[wave][k][lane] = mx[k] + base[k];
      Lsm[wave][k][lane] = sacc[k];
    }
    __syncthreads();
    if (wave < 2) {
      const int n = blockIdx.x * 128 + wave * 64 + lane;
      if (n < N) {
        float gm = Lmx[0][wave][lane];
#pragma unroll
        for (int v = 1; v < SPLIT; ++v) gm = fmaxf(gm, Lmx[v][wave][lane]);
        float S = 0.f;
#pragma unroll
        for (int v = 0; v < SPLIT; ++v)
          S += Lsm[v][wave][lane] * EXP2(Lmx[v][wave][lane] - gm);
        out[n] = (gm + __log2f(S)) * LN2;
      }
    }
  }
}

// ---------------- legacy exact fallback (R9b structure, logZ at output) ----
__global__ __launch_bounds__(512, 4) void gmix_kernel(
    const float* __restrict__ sample,
    const float* __restrict__ C,
    float* __restrict__ out,
    int N, int M) {
  __shared__ float Lmx[SPLIT][4][64];
  __shared__ float Lsm[SPLIT][4][64];

  const int lane = threadIdx.x & 63;
  const int wave = __builtin_amdgcn_readfirstlane((int)(threadIdx.x >> 6));
  const int n0 = blockIdx.x * 256 + lane;

  float2 xs0 = (n0       < N) ? ((const float2*)sample)[n0      ] : make_float2(0.f, 0.f);
  float2 xs1 = (n0 + 64  < N) ? ((const float2*)sample)[n0 + 64 ] : make_float2(0.f, 0.f);
  float2 xs2 = (n0 + 128 < N) ? ((const float2*)sample)[n0 + 128] : make_float2(0.f, 0.f);
  float2 xs3 = (n0 + 192 < N) ? ((const float2*)sample)[n0 + 192] : make_float2(0.f, 0.f);
  const v4f x0q = {xs0.x, xs1.x, xs2.x, xs3.x};
  const v4f x1q = {xs0.y, xs1.y, xs2.y, xs3.y};

  const int flag = ((const int*)C)[6 * M + 0];
  const float cb1 = C[6 * M + 1];
  const float cb3 = C[6 * M + 2];
  const float cb5 = C[6 * M + 3];
  const float logZh = C[6 * M + 4];

  const int Mq = M / SPLIT;
  const int m0 = wave * Mq;
  const float* __restrict__ C0 = C + m0;
  const float* __restrict__ C1 = C + M + m0;
  const float* __restrict__ C2 = C + 2 * M + m0;
  const float* __restrict__ C3 = C + 3 * M + m0;
  const float* __restrict__ C4 = C + 4 * M + m0;
  const float* __restrict__ C5 = C + 5 * M + m0;

  v4f base4 = {0.f, 0.f, 0.f, 0.f};
  v4f mx = {-INFINITY, -INFINITY, -INFINITY, -INFINITY};
  v4f s  = {0.f, 0.f, 0.f, 0.f};
  const v4f tminv4 = {SCH_TMIN, SCH_TMIN, SCH_TMIN, SCH_TMIN};
  const v4f logZ4 = {logZh, logZh, logZh, logZh};

  if (flag) {
    base4 = cb1 * x0q * x0q + cb3 * x1q * x1q + cb5 * x0q * x1q - logZ4;
    for (int m = 0; m < Mq; m += CH) {
      v4f a[CH];
#pragma unroll
      for (int j = 0; j < CH; ++j) {
        const float c0 = C0[m + j], c2 = C2[m + j], c4 = C4[m + j];
        v4f t = x0q * c2 + c0;
        a[j] = x1q * c4 + t;
      }
      v4f t0 = VMAX(a[0], a[1]);
      v4f t1 = VMAX(a[2], a[3]);
      v4f t2 = VMAX(a[4], a[5]);
      v4f t3 = VMAX(a[6], a[7]);
#pragma unroll
      for (int j = 8; j < CH; j += 4) {
        t0 = VMAX(t0, a[j]);     t1 = VMAX(t1, a[j + 1]);
        t2 = VMAX(t2, a[j + 2]); t3 = VMAX(t3, a[j + 3]);
      }
      const v4f cm = VMAX(VMAX(t0, t1), VMAX(t2, t3));
      const v4f nm = VMAX(mx, cm);
      v4f resc;
      resc.x = EXP2(mx.x - nm.x); resc.y = EXP2(mx.y - nm.y);
      resc.z = EXP2(mx.z - nm.z); resc.w = EXP2(mx.w - nm.w);
      const v4f knm = SCH_K2 - nm * SCH_K1;
      v4f l0 = {0.f, 0.f, 0.f, 0.f}, l1 = {0.f, 0.f, 0.f, 0.f};
#pragma unroll
      for (int j = 0; j < CH; j += 2) {
        v4f u0 = a[j]     * SCH_K1 + knm;
        v4f u1 = a[j + 1] * SCH_K1 + knm;
        u0 = VMAX(u0, tminv4);
        u1 = VMAX(u1, tminv4);
        const i4v iv0 = __builtin_convertvector(u0, i4v);
        const i4v iv1 = __builtin_convertvector(u1, i4v);
        l0 += __builtin_bit_cast(v4f, iv0);
        l1 += __builtin_bit_cast(v4f, iv1);
      }
      s = s * resc + (l0 + l1);
      mx = nm;
    }
  } else {
    base4 = cb1 * x0q * x0q + cb3 * x1q * x1q + cb5 * x0q * x1q - logZ4;
    for (int m = 0; m < Mq; m += CH) {
      v4f a[CH];
#pragma unroll
      for (int j = 0; j < CH; ++j) {
        const float c0 = C0[m + j], c1 = C1[m + j], c2 = C2[m + j];
        const float c3 = C3[m + j], c4 = C4[m + j], c5 = C5[m + j];
        v4f u = x0q * c1 + c2;
        u = x1q * c5 + u;
        v4f v = x1q * c3 + c4;
        v4f r = u * x0q + c0;
        a[j] = v * x1q + r;
      }
      v4f t0 = VMAX(a[0], a[1]);
      v4f t1 = VMAX(a[2], a[3]);
      v4f t2 = VMAX(a[4], a[5]);
      v4f t3 = VMAX(a[6], a[7]);
#pragma unroll
      for (int j = 8; j < CH; j += 4) {
        t0 = VMAX(t0, a[j]);     t1 = VMAX(t1, a[j + 1]);
        t2 = VMAX(t2, a[j + 2]); t3 = VMAX(t3, a[j + 3]);
      }
      const v4f cm = VMAX(VMAX(t0, t1), VMAX(t2, t3));
      const v4f nm = VMAX(mx, cm);
      v4f resc;
      resc.x = EXP2(mx.x - nm.x); resc.y = EXP2(mx.y - nm.y);
      resc.z = EXP2(mx.z - nm.z); resc.w = EXP2(mx.w - nm.w);
      v4f l0 = {0.f, 0.f, 0.f, 0.f}, l1 = {0.f, 0.f, 0.f, 0.f};
#pragma unroll
      for (int j = 0; j < CH; j += 2) {
        v4f d0 = a[j] - nm, d1 = a[j + 1] - nm;
        v4f e0, e1;
        e0.x = EXP2(d0.x); e0.y = EXP2(d0.y); e0.z = EXP2(d0.z); e0.w = EXP2(d0.w);
        e1.x = EXP2(d1.x); e1.y = EXP2(d1.y); e1.z = EXP2(d1.z); e1.w = EXP2(d1.w);
        l0 += e0; l1 += e1;
      }
      s = s * resc + (l0 + l1);
      mx = nm;
    }
  }

#pragma unroll
  for (int k = 0; k < 4; ++k) {
    Lmx[wave][k][lane] = mx[k] + base4[k];
    Lsm[wave][k][lane] = s[k];
  }
  __syncthreads();

  if (wave < 4) {
    const int set = wave;
    const int n = blockIdx.x * 256 + set * 64 + lane;
    if (n < N) {
      float gm = Lmx[0][set][lane];
#pragma unroll
      for (int v = 1; v < SPLIT; ++v) gm = fmaxf(gm, Lmx[v][set][lane]);
      float S = 0.f;
#pragma unroll
      for (int v = 0; v < SPLIT; ++v)
        S += Lsm[v][set][lane] * EXP2(Lmx[v][set][lane] - gm);
      out[n] = (gm + __log2f(S)) * LN2;
    }
  }
}

extern "C" void kernel_launch(void* const* d_in, const int* in_sizes, int n_in,
                              void* d_out, int out_size, void* d_ws, size_t ws_size,
                              hipStream_t stream) {
  const float* sample = (const float*)d_in[0];
  const float* mu     = (const float*)d_in[1];
  const float* A      = (const float*)d_in[2];
  const float* w      = (const float*)d_in[3];
  float* out = (float*)d_out;

  const int N = in_sizes[0] / 2;   // sample is (N,2)
  const int M = in_sizes[3];       // w is (M,1)

  float* C = (float*)d_ws;         // 6*M planes + 16-float header + Bpack[M][8]
  const size_t need = ((size_t)6 * M + 16) * 4 + (size_t)M * 16;

  const int prepBlocks = 1 + (M + 255) / 256;
  prep_kernel<<<prepBlocks, 256, 0, stream>>>(mu, A, w, C, M);

  if (ws_size >= need && M % (RMF * 16) == 0 && M % (SPLIT * CH) == 0) {
    gmix_mfma<<<(N + 127) / 128, 512, 0, stream>>>(
        (const float2*)sample, C, out, N, M);
  } else {
    gmix_kernel<<<(N + 255) / 256, 512, 0, stream>>>(sample, C, out, N, M);
  }
}